// Round 8
// baseline (277.481 us; speedup 1.0000x reference)
//
#include <hip/hip_runtime.h>

// ---------------------------------------------------------------------------
// Tensor_CSPNet forward, restructured:
//   out[b,o] = sum_h <G[o,h], log(V_h^T X[b,h] V_h + D_h)> + const[o]
// ReEig stages are provably no-ops (all eigenvalues >= 0.5 >> 1e-4).
// R16: prep Jacobi(bn,rm) -> block-parallel coupled Newton-Schulz (-13us).
// R17: prep G-pass coalesced (-9us).
// R18: FAILED. launch_bounds(256,8) -> 32-VGPR squeeze -> 1.3GB scratch spill.
// R19: FAILED. 4-wave blocks: occupancy is GRID-limited; 64-thr blocks right.
// R20: WIN (-40us main). Odd-even transposition (Brent-Luk) ordering.
// R21: WIN (-11us main). Direct c,s rotation (3 transcendentals) +
//   update_dpp boundary merge.
// R22/R23: packed-FP32 conversion (R22 bench was an infra failure --
//   "container failed twice", no kernel verdict; resubmitted unchanged).
//   Cycle model: ~19k scalar-FMA/lane -> 53us issue floor, measured 178us
//   @ 67% busy == the model with every v2f op costing TWO instructions.
//   Theory: hipcc scalarizes float2 math, never emitting v_pk_fma_f32
//   (VOP3P; the only path to the 157 TF fp32 peak = 2x the 78.6 TF
//   scalar-issue ceiling). Force VOP3P via inline asm in ALL hot v2f
//   paths of main (build, norms, Gram dots, rotation applies,
//   projection). Scalar rot math / DPP wiring / convergence unchanged.
//   If neutral: compiler was already packing -> kernel is at its
//   issue-bound structural floor.
// ---------------------------------------------------------------------------

#define WS_CONST 484                     // 4     : fc_w@conv_b + fc_b
#define WS_VT    512                     // 27*484: Vt[h][j][k] = V_h[k][j]
#define WS_V     (512 + 13068)           // 27*528: V[h][k][j], rows padded to 24
#define WS_D     (13580 + 14256)         // 27*484: D_h row-major (sym)
#define WS_G     (27836 + 13068)         // 4*27*528: G[o][h], rows padded to 24
#define G_STRIDE 528
#define V_STRIDE 528

typedef float v2f __attribute__((ext_vector_type(2)));

// ---- forced VOP3P packed-fp32 (v2f lives in an aligned VGPR pair) ---------
static __device__ __forceinline__ v2f pk_fma(v2f a, v2f b, v2f c) {  // a*b + c
  v2f d;
  asm("v_pk_fma_f32 %0, %1, %2, %3" : "=v"(d) : "v"(a), "v"(b), "v"(c));
  return d;
}
static __device__ __forceinline__ v2f pk_fma_nc(v2f a, v2f b, v2f c) { // a*b - c
  v2f d;
  asm("v_pk_fma_f32 %0, %1, %2, %3 neg_lo:[0,0,1] neg_hi:[0,0,1]"
      : "=v"(d) : "v"(a), "v"(b), "v"(c));
  return d;
}
static __device__ __forceinline__ v2f pk_mul(v2f a, v2f b) {          // a*b
  v2f d;
  asm("v_pk_mul_f32 %0, %1, %2" : "=v"(d) : "v"(a), "v"(b));
  return d;
}

static __device__ __forceinline__ float dpp_shl1(float x) { // lane m <- lane m+1 (within 16-row)
  return __int_as_float(__builtin_amdgcn_mov_dpp(__float_as_int(x), 0x101, 0xf, 0xf, true));
}
// lane m <- lane m-1 within 16-row; lane 0 of each row KEEPS old (bound_ctrl=false)
static __device__ __forceinline__ float upd_shr1(float old, float x) {
  return __int_as_float(__builtin_amdgcn_update_dpp(
      __float_as_int(old), __float_as_int(x), 0x111, 0xf, 0xf, false));
}

// Direct Jacobi rotation from Gram entries (nL, d, nR):
//   mu = (nR-nL)/2; r = sqrt(mu^2+d^2); cos2t = |mu|/r (inner rotation)
//   c = sqrt((1+cos2t)/2); cs2 = 2cs = sign(mu)*d/r; s = cs2/(2c)
// Identical rotation to the t-chain form; no division by d.
static __device__ __forceinline__ void rot_cs(float nL, float nR, float d,
                                              float& c, float& s,
                                              float& c2, float& ss, float& cs2) {
  float mu   = 0.5f*(nR - nL);
  float r2   = __builtin_fmaf(mu, mu, d*d);
  float invr = __builtin_amdgcn_rsqf(r2);
  bool  degen = (r2 < 1e-40f);
  float co = fminf(fabsf(mu)*invr, 1.0f);
  co = degen ? 1.0f : co;
  c2 = __builtin_fmaf(0.5f, co, 0.5f);
  c  = sqrtf(c2);
  float cinv = __builtin_amdgcn_rcpf(c);
  float t2 = d*invr;
  t2 = (mu < 0.0f) ? -t2 : t2;
  cs2 = degen ? 0.0f : t2;
  s  = 0.5f*cs2*cinv;
  ss = 1.0f - c2;
}

// One-sided Jacobi, odd-even transposition ordering (Brent-Luk).
// Lane m (m=0..10) holds columns c_{2m} (wl) and c_{2m+1} (wr); lanes 11..15
// mirror pair 10 and are inert (gated from sums; junk contained: only lane10
// reads lane11, in step B, where its rotation is forced to identity).
// Sweep = 11 double-steps (22 rounds) covering all 231 pairs.
// Convergence: offF2 (sum of d^2 over the sweep) <= eps2 * sum(lambda^2).
static __device__ __forceinline__ void jacobi_sweeps(v2f wl[11], v2f wr[11],
                                                     bool act, bool inert,
                                                     int minsweep, float eps2) {
  int okprev = 0;
  #pragma unroll 1
  for (int sweep = 0; sweep < 5; ++sweep) {
    if (sweep >= minsweep && __all(okprev)) break;
    // fresh norms each sweep
    v2f na = (v2f)(0.f), nb = (v2f)(0.f);
    #pragma unroll
    for (int i = 0; i < 11; ++i) { na = pk_fma(wl[i], wl[i], na); nb = pk_fma(wr[i], wr[i], nb); }
    float nL = na.x + na.y, nR = nb.x + nb.y;
    // Q = sum lambda_i^4 over the group's 22 columns (inert lanes gated out)
    float q = inert ? 0.f : (nL*nL + nR*nR);
    q += __shfl_xor(q, 1, 16);
    q += __shfl_xor(q, 2, 16);
    q += __shfl_xor(q, 4, 16);
    q += __shfl_xor(q, 8, 16);
    float dacc = 0.f;
    #pragma unroll 1
    for (int r = 0; r < 11; ++r) {
      // ---------- step A: rotate intra-lane pair (wl, wr); swap by rename ----
      {
        v2f da = (v2f)(0.f), db = (v2f)(0.f);
        #pragma unroll
        for (int i = 0; i < 10; i += 2) { da = pk_fma(wl[i], wr[i], da); db = pk_fma(wl[i+1], wr[i+1], db); }
        da = pk_fma(wl[10], wr[10], da);
        float d = (da.x + da.y) + (db.x + db.y);
        dacc += d*d;
        float c, s, c2, ss, cs2;
        rot_cs(nL, nR, d, c, s, c2, ss, cs2);
        float nLn = c2*nL - cs2*d + ss*nR;   // norm of rotated-left
        float nRn = ss*nL + cs2*d + c2*nR;   // norm of rotated-right
        v2f cv = (v2f)(c), sv = (v2f)(s);
        #pragma unroll
        for (int i = 0; i < 11; ++i) {
          v2f t1 = pk_mul(sv, wr[i]);
          v2f t2 = pk_mul(cv, wr[i]);
          v2f nl = pk_fma_nc(cv, wl[i], t1);   // c*wl - s*wr
          v2f nr = pk_fma(sv, wl[i], t2);      // s*wl + c*wr
          wl[i] = nr;                        // swap: pos 2m <- rotated-right
          wr[i] = nl;                        //       pos 2m+1 <- rotated-left
        }
        nL = nRn; nR = nLn;
      }
      // ---------- step B: u = shl(wl) = c_{2m+2}; rotate (wr, u), lanes m<10 --
      {
        v2f u[11];
        #pragma unroll
        for (int i = 0; i < 11; ++i) { u[i].x = dpp_shl1(wl[i].x); u[i].y = dpp_shl1(wl[i].y); }
        float nU = dpp_shl1(nL);
        v2f da = (v2f)(0.f), db = (v2f)(0.f);
        #pragma unroll
        for (int i = 0; i < 10; i += 2) { da = pk_fma(wr[i], u[i], da); db = pk_fma(wr[i+1], u[i+1], db); }
        da = pk_fma(wr[10], u[10], da);
        float d = (da.x + da.y) + (db.x + db.y);
        d = act ? d : 0.f;                   // lane>=10: identity rotation (c=1,s=0)
        dacc += d*d;
        float c, s, c2, ss, cs2;
        rot_cs(nR, nU, d, c, s, c2, ss, cs2);
        v2f cv = (v2f)(c), sv = (v2f)(s);
        #pragma unroll
        for (int i = 0; i < 11; ++i) {
          v2f t1 = pk_mul(sv, u[i]);
          v2f t2 = pk_mul(cv, u[i]);
          v2f rl = pk_fma_nc(cv, wr[i], t1);   // c*wr - s*u  -> pos 2m+2 (lane m+1's wl)
          v2f rr = pk_fma(sv, wr[i], t2);      // s*wr + c*u  -> pos 2m+1 (stays, if active)
          wr[i].x = act ? rr.x : wr[i].x;
          wr[i].y = act ? rr.y : wr[i].y;
          wl[i].x = upd_shr1(wl[i].x, rl.x); // lane0 keeps old via bound_ctrl
          wl[i].y = upd_shr1(wl[i].y, rl.y);
        }
        float nRn = ss*nR + cs2*d + c2*nU;   // norm of rotated-right
        float nLg = c2*nR - cs2*d + ss*nU;   // norm of rotated-left (gated lane: = nR)
        nR = act ? nRn : nR;
        nL = upd_shr1(nL, nLg);
      }
    }
    float ds = inert ? 0.f : dacc;     // gate junk/NaN AFTER accumulation
    ds += __shfl_xor(ds, 1, 16);
    ds += __shfl_xor(ds, 2, 16);
    ds += __shfl_xor(ds, 4, 16);
    ds += __shfl_xor(ds, 8, 16);
    okprev = (ds <= eps2*q);
  }
}

// ---------------- prep: NS(bn,rm) -> S -> per-h Vt, V, D, G ----------------
// Coupled Newton-Schulz (all 256 threads, LDS matmuls):
//   A' = A/||A||_F ; Y0=A', Z0=I
//   T = 3I - Z@Y ; Y <- 0.5*Y@T ; Z <- 0.5*T@Z     (K=11 iterations)
//   Y -> A'^{1/2}, Z -> A'^{-1/2}
// S = rm^{-1/2} @ bn^{1/2} = sqrt(c_bn/c_rm) * Z_rm @ Y_bn.
__global__ void prep_kernel(const float* __restrict__ rm, const float* __restrict__ bn,
                            const float* __restrict__ W1, const float* __restrict__ W2,
                            const float* __restrict__ conv_w, const float* __restrict__ fc_w,
                            const float* __restrict__ conv_b, const float* __restrict__ fc_b,
                            float* __restrict__ ws, float* __restrict__ out) {
  __shared__ float sW1[1024] __attribute__((aligned(16)));
  __shared__ float sW2[704]  __attribute__((aligned(16)));
  __shared__ float sY[2][2][484] __attribute__((aligned(16)));  // [mat][buf][..]
  __shared__ float sZ[2][2][484] __attribute__((aligned(16)));
  __shared__ float sT[2][484]    __attribute__((aligned(16)));
  __shared__ float sS[484]  __attribute__((aligned(16)));
  __shared__ float sU[704]  __attribute__((aligned(16)));
  __shared__ float sE[220]  __attribute__((aligned(16)));
  __shared__ float sG[1936] __attribute__((aligned(16)));
  __shared__ float sC[2];
  const int tid = threadIdx.x, h = blockIdx.x;

  if (h == 0)  // zero the atomic-add target (replaces memset dispatch)
    for (int idx = tid; idx < 2048; idx += 256) out[idx] = 0.f;

  // phase A: waves 0/1 compute Frobenius norms of bn/rm; waves 2/3 stage W1,W2
  const int wv = tid >> 6, ln = tid & 63;
  if (wv < 2) {
    const float* src = wv ? rm : bn;
    float s = 0.f;
    for (int i = ln; i < 484; i += 64) { float v = src[i]; s += v*v; }
    s += __shfl_xor(s, 1);  s += __shfl_xor(s, 2);  s += __shfl_xor(s, 4);
    s += __shfl_xor(s, 8);  s += __shfl_xor(s, 16); s += __shfl_xor(s, 32);
    if (ln == 0) sC[wv] = sqrtf(s);
  } else {
    const int t = tid - 128;
    for (int i = t; i < 1024; i += 128) sW1[i] = W1[h*1024 + i];
    for (int i = t; i < 704;  i += 128) sW2[i] = W2[h*704 + i];
  }
  __syncthreads();

  // phase B: init Y = A/c, Z = I for both matrices
  {
    const float ic0 = 1.0f/sC[0], ic1 = 1.0f/sC[1];
    for (int idx = tid; idx < 484; idx += 256) {
      const int i = idx/22, j = idx - 22*i;
      const float e = (i == j) ? 1.f : 0.f;
      sY[0][0][idx] = bn[idx]*ic0;  sZ[0][0][idx] = e;
      sY[1][0][idx] = rm[idx]*ic1;  sZ[1][0][idx] = e;
    }
  }
  __syncthreads();

  // phase C: K=11 coupled NS iterations (v2f column pairs: 22 rows x 11 pairs)
  int cur = 0;
  #pragma unroll 1
  for (int it = 0; it < 11; ++it) {
    // T = 3I - Z@Y (both matrices: 484 v2f elements)
    for (int idx = tid; idx < 484; idx += 256) {
      const int mt = (idx >= 242), r = idx - mt*242, i = r/11, jp = r - 11*i;
      const float* Zc = sZ[mt][cur];
      const float* Yc = sY[mt][cur];
      v2f acc = (v2f)(0.f);
      #pragma unroll
      for (int k = 0; k < 22; ++k)
        acc += *(const v2f*)(Yc + k*22 + 2*jp) * Zc[i*22 + k];
      v2f tv;
      tv.x = ((2*jp     == i) ? 3.f : 0.f) - acc.x;
      tv.y = ((2*jp + 1 == i) ? 3.f : 0.f) - acc.y;
      *(v2f*)(sT[mt] + i*22 + 2*jp) = tv;
    }
    __syncthreads();
    // Ynew = 0.5*Y@T ; Znew = 0.5*T@Z  (968 v2f elements)
    for (int idx = tid; idx < 968; idx += 256) {
      const int sel = idx/242, r = idx - 242*sel, i = r/11, jp = r - 11*i;
      const int mt = sel >> 1; const bool isZ = sel & 1;
      const float* A = isZ ? sT[mt] : sY[mt][cur];
      const float* B = isZ ? sZ[mt][cur] : sT[mt];
      v2f acc = (v2f)(0.f);
      #pragma unroll
      for (int k = 0; k < 22; ++k)
        acc += *(const v2f*)(B + k*22 + 2*jp) * A[i*22 + k];
      *(v2f*)((isZ ? sZ[mt][cur^1] : sY[mt][cur^1]) + i*22 + 2*jp) = 0.5f*acc;
    }
    __syncthreads();
    cur ^= 1;   // data now lives in buffer 'cur'
  }

  // phase D: S = sqrt(c_bn/c_rm)*Z_rm@Y_bn ; U = W1@W2 ; raw G (coalesced)
  {
    const float scale = sqrtf(sC[0]/sC[1]);
    const float* Zrm = sZ[1][cur];
    const float* Ybn = sY[0][cur];
    for (int idx = tid; idx < 484; idx += 256) {
      const int i = idx/22, j = idx - 22*i;
      float s = 0.f;
      for (int k = 0; k < 22; ++k) s += Zrm[i*22+k]*Ybn[k*22+j];
      sS[idx] = scale*s;
    }
  }
  for (int idx = tid; idx < 704; idx += 256) {
    const int n = idx/22, j = idx - 22*n;
    float s = 0.f;
    for (int k = 0; k < 32; ++k) s += sW1[n*32+k]*sW2[k*22+j];
    sU[idx] = s;
  }
  // raw G, coalesced: thread t owns v2f element r = 2t,2t+1 of all 4 outputs.
  if (tid < 242) {
    const int wi = h/9, bi = h - 9*wi;
    const float* base = conv_w + wi*4356 + bi*484 + 2*tid;
    v2f a0 = (v2f)(0.f), a1 = (v2f)(0.f), a2 = (v2f)(0.f), a3 = (v2f)(0.f);
    #pragma unroll
    for (int c = 0; c < 48; ++c) {
      const v2f wv2 = *(const v2f*)(base + c*13068);
      a0 += wv2*fc_w[c];
      a1 += wv2*fc_w[48+c];
      a2 += wv2*fc_w[96+c];
      a3 += wv2*fc_w[144+c];
    }
    *(v2f*)(sG +        2*tid) = a0;
    *(v2f*)(sG +  484 + 2*tid) = a1;
    *(v2f*)(sG +  968 + 2*tid) = a2;
    *(v2f*)(sG + 1452 + 2*tid) = a3;
  }
  __syncthreads();

  // V = U_top @ S: write transposed (Vt, packed) and row-major (stride 24)
  for (int idx = tid; idx < 484; idx += 256) {
    const int k = idx/22, j = idx - 22*k;
    float s = 0.f;
    for (int l = 0; l < 22; ++l) s += sU[k*22+l]*sS[l*22+j];
    ws[WS_VT + h*484 + j*22 + k] = s;
    ws[WS_V  + h*V_STRIDE + k*24 + j] = s;
  }
  // E = U_bot @ S (10x22)
  for (int idx = tid; idx < 220; idx += 256) {
    const int e = idx/22, j = idx - 22*e;
    float s = 0.f;
    for (int l = 0; l < 22; ++l) s += sU[(22+e)*22+l]*sS[l*22+j];
    sE[idx] = s;
  }
  __syncthreads();
  // D = E^T E (22x22, symmetric)
  for (int idx = tid; idx < 484; idx += 256) {
    const int i = idx/22, j = idx - 22*i;
    float s = 0.f;
    for (int e = 0; e < 10; ++e) s += sE[e*22+i]*sE[e*22+j];
    ws[WS_D + h*484 + idx] = s;
  }
  // G symmetrized into padded layout
  for (int idx = tid; idx < 1936; idx += 256) {
    const int o = idx/484, r = idx - 484*o, i = r/22, j = r - 22*i;
    const float v = 0.5f*(sG[o*484 + i*22 + j] + sG[o*484 + j*22 + i]);
    ws[WS_G + (o*27+h)*G_STRIDE + i*24 + j] = v;
  }
  if (h == 0 && tid < 4) {
    float s = 0.f;
    for (int c = 0; c < 48; ++c) s += fc_w[tid*48+c]*conv_b[c];
    ws[WS_CONST + tid] = s + fc_b[tid];
  }
}

// ---------------- main: P4 build + one-sided Jacobi + projection -----------
// h is wave-uniform -> V/D/G base pointers uniform -> scalar loads (SMEM).
// Zero LDS; 64-thread blocks (4 matrices) for even CU balance (R19: bigger
// blocks regressed; occupancy is grid-limited at 3.4 waves/SIMD).
__global__ void __launch_bounds__(64, 3) main_kernel(const float* __restrict__ x,
                                                     const float* __restrict__ ws,
                                                     float* __restrict__ out) {
  const int lane = threadIdx.x;
  const int g = lane >> 4, m = lane & 15;
  const int mm = (m < 10) ? m : 10;          // lanes 11..15 mirror pair 10 (inert)
  const int h  = blockIdx.x % 27;            // wave-uniform
  const int b  = (blockIdx.x/27)*4 + g;
  const int id = b*27 + h;                   // matrix index in x

  // V column pair 2mm, 2mm+1 (rows 2mm,2mm+1 of Vt; 44 contiguous floats)
  v2f vl[11], vrr[11];
  {
    const v2f* vb = (const v2f*)(ws + WS_VT + h*484 + mm*44);
    #pragma unroll
    for (int j = 0; j < 11; ++j) { vl[j] = vb[j]; vrr[j] = vb[11+j]; }
  }
  // init w = D rows 2mm, 2mm+1 (columns of symmetric D)
  v2f wl[11], wr[11];
  {
    const v2f* d2 = (const v2f*)(ws + WS_D + h*484 + mm*44);
    #pragma unroll
    for (int j = 0; j < 11; ++j) { wl[j] = d2[j]; wr[j] = d2[11+j]; }
  }
  // streamed build: for each row k, t_k = <Xrow_k, v>, then w += V[k][:] * t_k
  {
    const v2f* X2 = (const v2f*)(x + (size_t)id * 484);
    const float* Vrow = ws + WS_V + h*V_STRIDE;
    #pragma unroll 2
    for (int k = 0; k < 22; ++k) {
      v2f aL = (v2f)(0.f), aR = (v2f)(0.f);
      #pragma unroll
      for (int c = 0; c < 11; ++c) {
        v2f xv = X2[11*k + c];
        aL = pk_fma(xv, vl[c], aL);
        aR = pk_fma(xv, vrr[c], aR);
      }
      float tLk = aL.x + aL.y, tRk = aR.x + aR.y;
      v2f tLv = (v2f)(tLk), tRv = (v2f)(tRk);
      const v2f* vk = (const v2f*)(Vrow + k*24);
      #pragma unroll
      for (int j = 0; j < 11; ++j) {
        v2f q = vk[j];
        wl[j] = pk_fma(q, tLv, wl[j]);
        wr[j] = pk_fma(q, tRv, wr[j]);
      }
    }
  }

  jacobi_sweeps(wl, wr, (m < 10), (m > 10), 2, 1e-4f);

  // log-eig coefficients: L = sum_j (log lam_j / lam_j^2) w_j w_j^T, lam^2 = ||w||^2
  float nL, nR;
  {
    v2f na = (v2f)(0.f), nb = (v2f)(0.f);
    #pragma unroll
    for (int i = 0; i < 11; ++i) { na = pk_fma(wl[i], wl[i], na); nb = pk_fma(wr[i], wr[i], nb); }
    nL = na.x + na.y; nR = nb.x + nb.y;
  }
  const float HALF_LN2 = 0.34657359f;        // 0.5*ln(2)
  float coefL = HALF_LN2*log2f(fmaxf(nL, 1e-8f))*__builtin_amdgcn_rcpf(nL);
  float coefR = HALF_LN2*log2f(fmaxf(nR, 1e-8f))*__builtin_amdgcn_rcpf(nR);

  // projection: out[b,o] += sum_cols coef * (w^T G[o,h] w)
  #pragma unroll 1
  for (int o = 0; o < 4; ++o) {
    const float* Gptr = ws + WS_G + (o*27+h)*G_STRIDE;
    float qL = 0.f, qR = 0.f;
    #pragma unroll
    for (int k = 0; k < 22; ++k) {
      const v2f* g2 = (const v2f*)(Gptr + k*24);
      v2f sa = (v2f)(0.f), ra = (v2f)(0.f);
      #pragma unroll
      for (int j = 0; j < 11; ++j) {
        v2f q = g2[j];
        sa = pk_fma(q, wl[j], sa);
        ra = pk_fma(q, wr[j], ra);
      }
      float wLk = wl[k>>1][k&1], wRk = wr[k>>1][k&1];
      qL += wLk*(sa.x + sa.y);
      qR += wRk*(ra.x + ra.y);
    }
    float v = (m <= 10) ? (coefL*qL + coefR*qR) : 0.0f;
    v += __shfl_down(v, 8, 16);
    v += __shfl_down(v, 4, 16);
    v += __shfl_down(v, 2, 16);
    v += __shfl_down(v, 1, 16);
    if (m == 0) {
      if (h == 0) v += ws[WS_CONST + o];
      atomicAdd(out + b*4 + o, v);
    }
  }
}

extern "C" void kernel_launch(void* const* d_in, const int* in_sizes, int n_in,
                              void* d_out, int out_size, void* d_ws, size_t ws_size,
                              hipStream_t stream) {
  const float* x   = (const float*)d_in[0];
  const float* W1  = (const float*)d_in[1];
  const float* W2  = (const float*)d_in[2];
  const float* rm  = (const float*)d_in[3];
  const float* bn  = (const float*)d_in[4];
  const float* cw  = (const float*)d_in[5];
  const float* cb  = (const float*)d_in[6];
  const float* fw  = (const float*)d_in[7];
  const float* fb  = (const float*)d_in[8];
  float* out = (float*)d_out;
  float* ws  = (float*)d_ws;

  prep_kernel<<<27, 256, 0, stream>>>(rm, bn, W1, W2, cw, fw, cb, fb, ws, out);
  main_kernel<<<3456, 64, 0, stream>>>(x, ws, out);
}

// Round 10
// 260.248 us; speedup vs baseline: 1.0662x; 1.0662x over previous
//
#include <hip/hip_runtime.h>

// ---------------------------------------------------------------------------
// Tensor_CSPNet forward, restructured:
//   out[b,o] = sum_h <G[o,h], log(V_h^T X[b,h] V_h + D_h)> + const[o]
// ReEig stages are provably no-ops (all eigenvalues >= 0.5 >> 1e-4).
// R16: prep Jacobi(bn,rm) -> block-parallel coupled Newton-Schulz (-13us).
// R17: prep G-pass coalesced (-9us).
// R18: FAILED. launch_bounds(256,8) -> 32-VGPR squeeze -> 1.3GB scratch spill.
// R19: FAILED. 4-wave blocks: occupancy is GRID-limited; 64-thr blocks right.
// R20: WIN (-40us main). Odd-even transposition (Brent-Luk) ordering.
// R21: WIN (-11us main). Direct c,s rotation + update_dpp boundary merge.
// R22/R23: FAILED. v_pk_fma_f32: scalar v_fma IS the gfx950 fp32 peak
//   (157.3TF = 256x4x32x2x2.4GHz); VOP3P gains nothing, costs VGPR+sched.
// R24: FAILED accuracy (absmax 1.15e-2 > 8.6e-3): eps2 3e-3 too loose --
//   the 2-sweep exit path isn't one-full-sweep-better for clustered
//   eigenvalues. eps2=1e-4 is the validated accuracy boundary.
// R25: declared fallback = revert eps2 to 1e-4, KEEP triangle projection
//   (exact algebra: w^T G w = sum_k w_k sum_{j<=k} Gs_kj w_j with
//   half-scaled lower triangle; -45% of projection FMAs).
// ---------------------------------------------------------------------------

#define WS_CONST 484                     // 4     : fc_w@conv_b + fc_b
#define WS_VT    512                     // 27*484: Vt[h][j][k] = V_h[k][j]
#define WS_V     (512 + 13068)           // 27*528: V[h][k][j], rows padded to 24
#define WS_D     (13580 + 14256)         // 27*484: D_h row-major (sym)
#define WS_G     (27836 + 13068)         // 4*27*528: Gs[o][h] half-scaled, rows padded to 24
#define G_STRIDE 528
#define V_STRIDE 528

typedef float v2f __attribute__((ext_vector_type(2)));

static __device__ __forceinline__ float dpp_shl1(float x) { // lane m <- lane m+1 (within 16-row)
  return __int_as_float(__builtin_amdgcn_mov_dpp(__float_as_int(x), 0x101, 0xf, 0xf, true));
}
// lane m <- lane m-1 within 16-row; lane 0 of each row KEEPS old (bound_ctrl=false)
static __device__ __forceinline__ float upd_shr1(float old, float x) {
  return __int_as_float(__builtin_amdgcn_update_dpp(
      __float_as_int(old), __float_as_int(x), 0x111, 0xf, 0xf, false));
}

// Direct Jacobi rotation from Gram entries (nL, d, nR):
//   mu = (nR-nL)/2; r = sqrt(mu^2+d^2); cos2t = |mu|/r (inner rotation)
//   c = sqrt((1+cos2t)/2); cs2 = 2cs = sign(mu)*d/r; s = cs2/(2c)
// Identical rotation to the t-chain form; no division by d.
static __device__ __forceinline__ void rot_cs(float nL, float nR, float d,
                                              float& c, float& s,
                                              float& c2, float& ss, float& cs2) {
  float mu   = 0.5f*(nR - nL);
  float r2   = __builtin_fmaf(mu, mu, d*d);
  float invr = __builtin_amdgcn_rsqf(r2);
  bool  degen = (r2 < 1e-40f);
  float co = fminf(fabsf(mu)*invr, 1.0f);
  co = degen ? 1.0f : co;
  c2 = __builtin_fmaf(0.5f, co, 0.5f);
  c  = sqrtf(c2);
  float cinv = __builtin_amdgcn_rcpf(c);
  float t2 = d*invr;
  t2 = (mu < 0.0f) ? -t2 : t2;
  cs2 = degen ? 0.0f : t2;
  s  = 0.5f*cs2*cinv;
  ss = 1.0f - c2;
}

// One-sided Jacobi, odd-even transposition ordering (Brent-Luk).
// Lane m (m=0..10) holds columns c_{2m} (wl) and c_{2m+1} (wr); lanes 11..15
// mirror pair 10 and are inert (gated from sums; junk contained: only lane10
// reads lane11, in step B, where its rotation is forced to identity).
// Sweep = 11 double-steps (22 rounds) covering all 231 pairs.
// Convergence: offF2 (sum of d^2 over the sweep) <= eps2 * sum(lambda^2).
static __device__ __forceinline__ void jacobi_sweeps(v2f wl[11], v2f wr[11],
                                                     bool act, bool inert,
                                                     int minsweep, float eps2) {
  int okprev = 0;
  #pragma unroll 1
  for (int sweep = 0; sweep < 5; ++sweep) {
    if (sweep >= minsweep && __all(okprev)) break;
    // fresh norms each sweep
    v2f na = (v2f)(0.f), nb = (v2f)(0.f);
    #pragma unroll
    for (int i = 0; i < 11; ++i) { na += wl[i]*wl[i]; nb += wr[i]*wr[i]; }
    float nL = na.x + na.y, nR = nb.x + nb.y;
    // Q = sum lambda_i^4 over the group's 22 columns (inert lanes gated out)
    float q = inert ? 0.f : (nL*nL + nR*nR);
    q += __shfl_xor(q, 1, 16);
    q += __shfl_xor(q, 2, 16);
    q += __shfl_xor(q, 4, 16);
    q += __shfl_xor(q, 8, 16);
    float dacc = 0.f;
    #pragma unroll 1
    for (int r = 0; r < 11; ++r) {
      // ---------- step A: rotate intra-lane pair (wl, wr); swap by rename ----
      {
        v2f da = (v2f)(0.f), db = (v2f)(0.f);
        #pragma unroll
        for (int i = 0; i < 10; i += 2) { da += wl[i]*wr[i]; db += wl[i+1]*wr[i+1]; }
        da += wl[10]*wr[10];
        float d = (da.x + da.y) + (db.x + db.y);
        dacc += d*d;
        float c, s, c2, ss, cs2;
        rot_cs(nL, nR, d, c, s, c2, ss, cs2);
        float nLn = c2*nL - cs2*d + ss*nR;   // norm of rotated-left
        float nRn = ss*nL + cs2*d + c2*nR;   // norm of rotated-right
        v2f cv = (v2f)(c), sv = (v2f)(s);
        #pragma unroll
        for (int i = 0; i < 11; ++i) {
          v2f nl = cv*wl[i] - sv*wr[i];
          v2f nr = sv*wl[i] + cv*wr[i];
          wl[i] = nr;                        // swap: pos 2m <- rotated-right
          wr[i] = nl;                        //       pos 2m+1 <- rotated-left
        }
        nL = nRn; nR = nLn;
      }
      // ---------- step B: u = shl(wl) = c_{2m+2}; rotate (wr, u), lanes m<10 --
      {
        v2f u[11];
        #pragma unroll
        for (int i = 0; i < 11; ++i) { u[i].x = dpp_shl1(wl[i].x); u[i].y = dpp_shl1(wl[i].y); }
        float nU = dpp_shl1(nL);
        v2f da = (v2f)(0.f), db = (v2f)(0.f);
        #pragma unroll
        for (int i = 0; i < 10; i += 2) { da += wr[i]*u[i]; db += wr[i+1]*u[i+1]; }
        da += wr[10]*u[10];
        float d = (da.x + da.y) + (db.x + db.y);
        d = act ? d : 0.f;                   // lane>=10: identity rotation (c=1,s=0)
        dacc += d*d;
        float c, s, c2, ss, cs2;
        rot_cs(nR, nU, d, c, s, c2, ss, cs2);
        v2f cv = (v2f)(c), sv = (v2f)(s);
        #pragma unroll
        for (int i = 0; i < 11; ++i) {
          v2f rl = cv*wr[i] - sv*u[i];       // rotated-left  -> pos 2m+2 (lane m+1's wl)
          v2f rr = sv*wr[i] + cv*u[i];       // rotated-right -> pos 2m+1 (stays, if active)
          wr[i].x = act ? rr.x : wr[i].x;
          wr[i].y = act ? rr.y : wr[i].y;
          wl[i].x = upd_shr1(wl[i].x, rl.x); // lane0 keeps old via bound_ctrl
          wl[i].y = upd_shr1(wl[i].y, rl.y);
        }
        float nRn = ss*nR + cs2*d + c2*nU;   // norm of rotated-right
        float nLg = c2*nR - cs2*d + ss*nU;   // norm of rotated-left (gated lane: = nR)
        nR = act ? nRn : nR;
        nL = upd_shr1(nL, nLg);
      }
    }
    float ds = inert ? 0.f : dacc;     // gate junk/NaN AFTER accumulation
    ds += __shfl_xor(ds, 1, 16);
    ds += __shfl_xor(ds, 2, 16);
    ds += __shfl_xor(ds, 4, 16);
    ds += __shfl_xor(ds, 8, 16);
    okprev = (ds <= eps2*q);
  }
}

// ---------------- prep: NS(bn,rm) -> S -> per-h Vt, V, D, G ----------------
// Coupled Newton-Schulz (all 256 threads, LDS matmuls):
//   A' = A/||A||_F ; Y0=A', Z0=I
//   T = 3I - Z@Y ; Y <- 0.5*Y@T ; Z <- 0.5*T@Z     (K=11 iterations)
//   Y -> A'^{1/2}, Z -> A'^{-1/2}
// S = rm^{-1/2} @ bn^{1/2} = sqrt(c_bn/c_rm) * Z_rm @ Y_bn.
__global__ void prep_kernel(const float* __restrict__ rm, const float* __restrict__ bn,
                            const float* __restrict__ W1, const float* __restrict__ W2,
                            const float* __restrict__ conv_w, const float* __restrict__ fc_w,
                            const float* __restrict__ conv_b, const float* __restrict__ fc_b,
                            float* __restrict__ ws, float* __restrict__ out) {
  __shared__ float sW1[1024] __attribute__((aligned(16)));
  __shared__ float sW2[704]  __attribute__((aligned(16)));
  __shared__ float sY[2][2][484] __attribute__((aligned(16)));  // [mat][buf][..]
  __shared__ float sZ[2][2][484] __attribute__((aligned(16)));
  __shared__ float sT[2][484]    __attribute__((aligned(16)));
  __shared__ float sS[484]  __attribute__((aligned(16)));
  __shared__ float sU[704]  __attribute__((aligned(16)));
  __shared__ float sE[220]  __attribute__((aligned(16)));
  __shared__ float sG[1936] __attribute__((aligned(16)));
  __shared__ float sC[2];
  const int tid = threadIdx.x, h = blockIdx.x;

  if (h == 0)  // zero the atomic-add target (replaces memset dispatch)
    for (int idx = tid; idx < 2048; idx += 256) out[idx] = 0.f;

  // phase A: waves 0/1 compute Frobenius norms of bn/rm; waves 2/3 stage W1,W2
  const int wv = tid >> 6, ln = tid & 63;
  if (wv < 2) {
    const float* src = wv ? rm : bn;
    float s = 0.f;
    for (int i = ln; i < 484; i += 64) { float v = src[i]; s += v*v; }
    s += __shfl_xor(s, 1);  s += __shfl_xor(s, 2);  s += __shfl_xor(s, 4);
    s += __shfl_xor(s, 8);  s += __shfl_xor(s, 16); s += __shfl_xor(s, 32);
    if (ln == 0) sC[wv] = sqrtf(s);
  } else {
    const int t = tid - 128;
    for (int i = t; i < 1024; i += 128) sW1[i] = W1[h*1024 + i];
    for (int i = t; i < 704;  i += 128) sW2[i] = W2[h*704 + i];
  }
  __syncthreads();

  // phase B: init Y = A/c, Z = I for both matrices
  {
    const float ic0 = 1.0f/sC[0], ic1 = 1.0f/sC[1];
    for (int idx = tid; idx < 484; idx += 256) {
      const int i = idx/22, j = idx - 22*i;
      const float e = (i == j) ? 1.f : 0.f;
      sY[0][0][idx] = bn[idx]*ic0;  sZ[0][0][idx] = e;
      sY[1][0][idx] = rm[idx]*ic1;  sZ[1][0][idx] = e;
    }
  }
  __syncthreads();

  // phase C: K=11 coupled NS iterations (v2f column pairs: 22 rows x 11 pairs)
  int cur = 0;
  #pragma unroll 1
  for (int it = 0; it < 11; ++it) {
    // T = 3I - Z@Y (both matrices: 484 v2f elements)
    for (int idx = tid; idx < 484; idx += 256) {
      const int mt = (idx >= 242), r = idx - mt*242, i = r/11, jp = r - 11*i;
      const float* Zc = sZ[mt][cur];
      const float* Yc = sY[mt][cur];
      v2f acc = (v2f)(0.f);
      #pragma unroll
      for (int k = 0; k < 22; ++k)
        acc += *(const v2f*)(Yc + k*22 + 2*jp) * Zc[i*22 + k];
      v2f tv;
      tv.x = ((2*jp     == i) ? 3.f : 0.f) - acc.x;
      tv.y = ((2*jp + 1 == i) ? 3.f : 0.f) - acc.y;
      *(v2f*)(sT[mt] + i*22 + 2*jp) = tv;
    }
    __syncthreads();
    // Ynew = 0.5*Y@T ; Znew = 0.5*T@Z  (968 v2f elements)
    for (int idx = tid; idx < 968; idx += 256) {
      const int sel = idx/242, r = idx - 242*sel, i = r/11, jp = r - 11*i;
      const int mt = sel >> 1; const bool isZ = sel & 1;
      const float* A = isZ ? sT[mt] : sY[mt][cur];
      const float* B = isZ ? sZ[mt][cur] : sT[mt];
      v2f acc = (v2f)(0.f);
      #pragma unroll
      for (int k = 0; k < 22; ++k)
        acc += *(const v2f*)(B + k*22 + 2*jp) * A[i*22 + k];
      *(v2f*)((isZ ? sZ[mt][cur^1] : sY[mt][cur^1]) + i*22 + 2*jp) = 0.5f*acc;
    }
    __syncthreads();
    cur ^= 1;   // data now lives in buffer 'cur'
  }

  // phase D: S = sqrt(c_bn/c_rm)*Z_rm@Y_bn ; U = W1@W2 ; raw G (coalesced)
  {
    const float scale = sqrtf(sC[0]/sC[1]);
    const float* Zrm = sZ[1][cur];
    const float* Ybn = sY[0][cur];
    for (int idx = tid; idx < 484; idx += 256) {
      const int i = idx/22, j = idx - 22*i;
      float s = 0.f;
      for (int k = 0; k < 22; ++k) s += Zrm[i*22+k]*Ybn[k*22+j];
      sS[idx] = scale*s;
    }
  }
  for (int idx = tid; idx < 704; idx += 256) {
    const int n = idx/22, j = idx - 22*n;
    float s = 0.f;
    for (int k = 0; k < 32; ++k) s += sW1[n*32+k]*sW2[k*22+j];
    sU[idx] = s;
  }
  // raw G, coalesced: thread t owns v2f element r = 2t,2t+1 of all 4 outputs.
  if (tid < 242) {
    const int wi = h/9, bi = h - 9*wi;
    const float* base = conv_w + wi*4356 + bi*484 + 2*tid;
    v2f a0 = (v2f)(0.f), a1 = (v2f)(0.f), a2 = (v2f)(0.f), a3 = (v2f)(0.f);
    #pragma unroll
    for (int c = 0; c < 48; ++c) {
      const v2f wv2 = *(const v2f*)(base + c*13068);
      a0 += wv2*fc_w[c];
      a1 += wv2*fc_w[48+c];
      a2 += wv2*fc_w[96+c];
      a3 += wv2*fc_w[144+c];
    }
    *(v2f*)(sG +        2*tid) = a0;
    *(v2f*)(sG +  484 + 2*tid) = a1;
    *(v2f*)(sG +  968 + 2*tid) = a2;
    *(v2f*)(sG + 1452 + 2*tid) = a3;
  }
  __syncthreads();

  // V = U_top @ S: write transposed (Vt, packed) and row-major (stride 24)
  for (int idx = tid; idx < 484; idx += 256) {
    const int k = idx/22, j = idx - 22*k;
    float s = 0.f;
    for (int l = 0; l < 22; ++l) s += sU[k*22+l]*sS[l*22+j];
    ws[WS_VT + h*484 + j*22 + k] = s;
    ws[WS_V  + h*V_STRIDE + k*24 + j] = s;
  }
  // E = U_bot @ S (10x22)
  for (int idx = tid; idx < 220; idx += 256) {
    const int e = idx/22, j = idx - 22*e;
    float s = 0.f;
    for (int l = 0; l < 22; ++l) s += sU[(22+e)*22+l]*sS[l*22+j];
    sE[idx] = s;
  }
  __syncthreads();
  // D = E^T E (22x22, symmetric)
  for (int idx = tid; idx < 484; idx += 256) {
    const int i = idx/22, j = idx - 22*i;
    float s = 0.f;
    for (int e = 0; e < 10; ++e) s += sE[e*22+i]*sE[e*22+j];
    ws[WS_D + h*484 + idx] = s;
  }
  // G symmetrized + HALF-SCALED into padded layout:
  //   Gs[i][j] = 2*Gsym_ij (j<i), Gsym_ii (j==i), 0 (j>i)
  // so that w^T G w = sum_i w_i * sum_{j<=i} Gs_ij w_j  (triangle projection)
  for (int idx = tid; idx < 1936; idx += 256) {
    const int o = idx/484, r = idx - 484*o, i = r/22, j = r - 22*i;
    const float v = 0.5f*(sG[o*484 + i*22 + j] + sG[o*484 + j*22 + i]);
    const float gs = (j < i) ? 2.0f*v : ((j == i) ? v : 0.0f);
    ws[WS_G + (o*27+h)*G_STRIDE + i*24 + j] = gs;
  }
  if (h == 0 && tid < 4) {
    float s = 0.f;
    for (int c = 0; c < 48; ++c) s += fc_w[tid*48+c]*conv_b[c];
    ws[WS_CONST + tid] = s + fc_b[tid];
  }
}

// ---------------- main: P4 build + one-sided Jacobi + projection -----------
// h is wave-uniform -> V/D/G base pointers uniform -> scalar loads (SMEM).
// Zero LDS; 64-thread blocks (4 matrices) for even CU balance (R19: bigger
// blocks regressed; occupancy is grid-limited at 3.4 waves/SIMD).
__global__ void __launch_bounds__(64, 3) main_kernel(const float* __restrict__ x,
                                                     const float* __restrict__ ws,
                                                     float* __restrict__ out) {
  const int lane = threadIdx.x;
  const int g = lane >> 4, m = lane & 15;
  const int mm = (m < 10) ? m : 10;          // lanes 11..15 mirror pair 10 (inert)
  const int h  = blockIdx.x % 27;            // wave-uniform
  const int b  = (blockIdx.x/27)*4 + g;
  const int id = b*27 + h;                   // matrix index in x

  // V column pair 2mm, 2mm+1 (rows 2mm,2mm+1 of Vt; 44 contiguous floats)
  v2f vl[11], vrr[11];
  {
    const v2f* vb = (const v2f*)(ws + WS_VT + h*484 + mm*44);
    #pragma unroll
    for (int j = 0; j < 11; ++j) { vl[j] = vb[j]; vrr[j] = vb[11+j]; }
  }
  // init w = D rows 2mm, 2mm+1 (columns of symmetric D)
  v2f wl[11], wr[11];
  {
    const v2f* d2 = (const v2f*)(ws + WS_D + h*484 + mm*44);
    #pragma unroll
    for (int j = 0; j < 11; ++j) { wl[j] = d2[j]; wr[j] = d2[11+j]; }
  }
  // streamed build: for each row k, t_k = <Xrow_k, v>, then w += V[k][:] * t_k
  {
    const v2f* X2 = (const v2f*)(x + (size_t)id * 484);
    const float* Vrow = ws + WS_V + h*V_STRIDE;
    #pragma unroll 2
    for (int k = 0; k < 22; ++k) {
      v2f aL = (v2f)(0.f), aR = (v2f)(0.f);
      #pragma unroll
      for (int c = 0; c < 11; ++c) {
        v2f xv = X2[11*k + c];
        aL += xv*vl[c];
        aR += xv*vrr[c];
      }
      float tLk = aL.x + aL.y, tRk = aR.x + aR.y;
      const v2f* vk = (const v2f*)(Vrow + k*24);
      #pragma unroll
      for (int j = 0; j < 11; ++j) {
        v2f q = vk[j];
        wl[j] += q*tLk;
        wr[j] += q*tRk;
      }
    }
  }

  jacobi_sweeps(wl, wr, (m < 10), (m > 10), 2, 1e-4f);

  // log-eig coefficients: L = sum_j (log lam_j / lam_j^2) w_j w_j^T, lam^2 = ||w||^2
  float nL, nR;
  {
    v2f na = (v2f)(0.f), nb = (v2f)(0.f);
    #pragma unroll
    for (int i = 0; i < 11; ++i) { na += wl[i]*wl[i]; nb += wr[i]*wr[i]; }
    nL = na.x + na.y; nR = nb.x + nb.y;
  }
  const float HALF_LN2 = 0.34657359f;        // 0.5*ln(2)
  float coefL = HALF_LN2*log2f(fmaxf(nL, 1e-8f))*__builtin_amdgcn_rcpf(nL);
  float coefR = HALF_LN2*log2f(fmaxf(nR, 1e-8f))*__builtin_amdgcn_rcpf(nR);

  // triangle projection: out[b,o] += coef * sum_k w_k (sum_{j<=k} Gs_kj w_j)
  #pragma unroll 1
  for (int o = 0; o < 4; ++o) {
    const float* Gptr = ws + WS_G + (o*27+h)*G_STRIDE;
    float qL = 0.f, qR = 0.f;
    #pragma unroll
    for (int k = 0; k < 22; ++k) {
      const v2f* g2 = (const v2f*)(Gptr + k*24);
      v2f sa = (v2f)(0.f), ra = (v2f)(0.f);
      #pragma unroll
      for (int j = 0; j <= (k>>1); ++j) {     // Gs zero beyond column k
        v2f q = g2[j];
        sa += q*wl[j];
        ra += q*wr[j];
      }
      float wLk = wl[k>>1][k&1], wRk = wr[k>>1][k&1];
      qL += wLk*(sa.x + sa.y);
      qR += wRk*(ra.x + ra.y);
    }
    float v = (m <= 10) ? (coefL*qL + coefR*qR) : 0.0f;
    v += __shfl_down(v, 8, 16);
    v += __shfl_down(v, 4, 16);
    v += __shfl_down(v, 2, 16);
    v += __shfl_down(v, 1, 16);
    if (m == 0) {
      if (h == 0) v += ws[WS_CONST + o];
      atomicAdd(out + b*4 + o, v);
    }
  }
}

extern "C" void kernel_launch(void* const* d_in, const int* in_sizes, int n_in,
                              void* d_out, int out_size, void* d_ws, size_t ws_size,
                              hipStream_t stream) {
  const float* x   = (const float*)d_in[0];
  const float* W1  = (const float*)d_in[1];
  const float* W2  = (const float*)d_in[2];
  const float* rm  = (const float*)d_in[3];
  const float* bn  = (const float*)d_in[4];
  const float* cw  = (const float*)d_in[5];
  const float* cb  = (const float*)d_in[6];
  const float* fw  = (const float*)d_in[7];
  const float* fb  = (const float*)d_in[8];
  float* out = (float*)d_out;
  float* ws  = (float*)d_ws;

  prep_kernel<<<27, 256, 0, stream>>>(rm, bn, W1, W2, cw, fw, cb, fb, ws, out);
  main_kernel<<<3456, 64, 0, stream>>>(x, ws, out);
}

// Round 11
// 260.230 us; speedup vs baseline: 1.0663x; 1.0001x over previous
//
#include <hip/hip_runtime.h>

// ---------------------------------------------------------------------------
// Tensor_CSPNet forward, restructured:
//   out[b,o] = sum_h <G[o,h], log(V_h^T X[b,h] V_h + D_h)> + const[o]
// ReEig stages are provably no-ops (all eigenvalues >= 0.5 >> 1e-4).
// R16: prep Jacobi(bn,rm) -> block-parallel coupled Newton-Schulz (-13us).
// R17: prep G-pass coalesced (-9us).
// R18: FAILED. launch_bounds(256,8) -> 32-VGPR squeeze -> 1.3GB scratch spill.
// R19: FAILED. 4-wave blocks: occupancy is GRID/equilibrium-limited.
// R20: WIN (-40us main). Odd-even transposition (Brent-Luk) ordering.
// R21: WIN (-11us main). Direct c,s rotation + update_dpp boundary merge.
// R22/R23: FAILED. v_pk_fma_f32: scalar v_fma IS the gfx950 fp32 peak.
// R24: FAILED accuracy: eps2 3e-3 too loose. eps2=1e-4 is the boundary.
// R25: WIN (-8us main). Triangle projection (exact) at eps2=1e-4.
// R26: dual-matrix interleave. main is latency-bound: VALUBusy 65% at
//   ~1.8 waves/SIMD; the stall is rot_cs's ~8-deep serial transcendental
//   chain (no intra-lane ILP), and occupancy won't rise (R19). Fix: each
//   thread carries TWO matrices (b1=base+g, b2=base+4+g; grid 1728=27x64);
//   the round body computes both matrices' dot/rot/apply in one basic
//   block so matrix-2's chain fills matrix-1's stalls. D-init, Vt, V-rows
//   and G loads are h-only -> shared across both matrices. Convergence
//   loop shared (exit when all 8 matrices pass; extra sweeps on early
//   converged ones are near-identity -> accuracy same-or-better).
//   VGPR peak ~155 (88 w + 44 u + temps) -> launch_bounds(64,2), no
//   spill (R18 tripwire: WRITE_SIZE must stay ~864KB).
// ---------------------------------------------------------------------------

#define WS_CONST 484                     // 4     : fc_w@conv_b + fc_b
#define WS_VT    512                     // 27*484: Vt[h][j][k] = V_h[k][j]
#define WS_V     (512 + 13068)           // 27*528: V[h][k][j], rows padded to 24
#define WS_D     (13580 + 14256)         // 27*484: D_h row-major (sym)
#define WS_G     (27836 + 13068)         // 4*27*528: Gs[o][h] half-scaled, rows padded to 24
#define G_STRIDE 528
#define V_STRIDE 528

typedef float v2f __attribute__((ext_vector_type(2)));

static __device__ __forceinline__ float dpp_shl1(float x) { // lane m <- lane m+1 (within 16-row)
  return __int_as_float(__builtin_amdgcn_mov_dpp(__float_as_int(x), 0x101, 0xf, 0xf, true));
}
// lane m <- lane m-1 within 16-row; lane 0 of each row KEEPS old (bound_ctrl=false)
static __device__ __forceinline__ float upd_shr1(float old, float x) {
  return __int_as_float(__builtin_amdgcn_update_dpp(
      __float_as_int(old), __float_as_int(x), 0x111, 0xf, 0xf, false));
}

// Direct Jacobi rotation from Gram entries (nL, d, nR):
//   mu = (nR-nL)/2; r = sqrt(mu^2+d^2); cos2t = |mu|/r (inner rotation)
//   c = sqrt((1+cos2t)/2); cs2 = 2cs = sign(mu)*d/r; s = cs2/(2c)
static __device__ __forceinline__ void rot_cs(float nL, float nR, float d,
                                              float& c, float& s,
                                              float& c2, float& ss, float& cs2) {
  float mu   = 0.5f*(nR - nL);
  float r2   = __builtin_fmaf(mu, mu, d*d);
  float invr = __builtin_amdgcn_rsqf(r2);
  bool  degen = (r2 < 1e-40f);
  float co = fminf(fabsf(mu)*invr, 1.0f);
  co = degen ? 1.0f : co;
  c2 = __builtin_fmaf(0.5f, co, 0.5f);
  c  = sqrtf(c2);
  float cinv = __builtin_amdgcn_rcpf(c);
  float t2 = d*invr;
  t2 = (mu < 0.0f) ? -t2 : t2;
  cs2 = degen ? 0.0f : t2;
  s  = 0.5f*cs2*cinv;
  ss = 1.0f - c2;
}

// One-sided Jacobi, odd-even transposition (Brent-Luk), TWO matrices per
// thread interleaved so their serial rotation chains cover each other's
// latency. Lane m holds cols (2m,2m+1) of both; lanes 11..15 inert.
static __device__ __forceinline__ void jacobi_sweeps2(v2f wl1[11], v2f wr1[11],
                                                      v2f wl2[11], v2f wr2[11],
                                                      bool act, bool inert,
                                                      int minsweep, float eps2) {
  int okprev = 0;
  #pragma unroll 1
  for (int sweep = 0; sweep < 5; ++sweep) {
    if (sweep >= minsweep && __all(okprev)) break;
    // fresh norms each sweep
    v2f na1 = (v2f)(0.f), nb1 = (v2f)(0.f), na2 = (v2f)(0.f), nb2 = (v2f)(0.f);
    #pragma unroll
    for (int i = 0; i < 11; ++i) {
      na1 += wl1[i]*wl1[i]; nb1 += wr1[i]*wr1[i];
      na2 += wl2[i]*wl2[i]; nb2 += wr2[i]*wr2[i];
    }
    float nL1 = na1.x + na1.y, nR1 = nb1.x + nb1.y;
    float nL2 = na2.x + na2.y, nR2 = nb2.x + nb2.y;
    float q1 = inert ? 0.f : (nL1*nL1 + nR1*nR1);
    float q2 = inert ? 0.f : (nL2*nL2 + nR2*nR2);
    q1 += __shfl_xor(q1, 1, 16);  q2 += __shfl_xor(q2, 1, 16);
    q1 += __shfl_xor(q1, 2, 16);  q2 += __shfl_xor(q2, 2, 16);
    q1 += __shfl_xor(q1, 4, 16);  q2 += __shfl_xor(q2, 4, 16);
    q1 += __shfl_xor(q1, 8, 16);  q2 += __shfl_xor(q2, 8, 16);
    float dacc1 = 0.f, dacc2 = 0.f;
    #pragma unroll 1
    for (int r = 0; r < 11; ++r) {
      // ---------- step A: rotate intra-lane pairs; swap by rename ----------
      {
        v2f da1 = (v2f)(0.f), da2 = (v2f)(0.f);
        #pragma unroll
        for (int i = 0; i < 11; ++i) { da1 += wl1[i]*wr1[i]; da2 += wl2[i]*wr2[i]; }
        float d1 = da1.x + da1.y, d2v = da2.x + da2.y;
        dacc1 += d1*d1; dacc2 += d2v*d2v;
        float c1, s1, c21, ss1, cs21; rot_cs(nL1, nR1, d1,  c1, s1, c21, ss1, cs21);
        float c2_, s2_, c22, ss2, cs22; rot_cs(nL2, nR2, d2v, c2_, s2_, c22, ss2, cs22);
        float nLn1 = c21*nL1 - cs21*d1 + ss1*nR1;
        float nRn1 = ss1*nL1 + cs21*d1 + c21*nR1;
        float nLn2 = c22*nL2 - cs22*d2v + ss2*nR2;
        float nRn2 = ss2*nL2 + cs22*d2v + c22*nR2;
        v2f cv1 = (v2f)(c1), sv1 = (v2f)(s1);
        v2f cv2 = (v2f)(c2_), sv2 = (v2f)(s2_);
        #pragma unroll
        for (int i = 0; i < 11; ++i) {
          v2f nl1 = cv1*wl1[i] - sv1*wr1[i];
          v2f nr1 = sv1*wl1[i] + cv1*wr1[i];
          wl1[i] = nr1; wr1[i] = nl1;
          v2f nl2 = cv2*wl2[i] - sv2*wr2[i];
          v2f nr2 = sv2*wl2[i] + cv2*wr2[i];
          wl2[i] = nr2; wr2[i] = nl2;
        }
        nL1 = nRn1; nR1 = nLn1;
        nL2 = nRn2; nR2 = nLn2;
      }
      // ---------- step B: u = shl(wl); rotate (wr, u), lanes m<10 ----------
      {
        v2f u1[11], u2[11];
        #pragma unroll
        for (int i = 0; i < 11; ++i) {
          u1[i].x = dpp_shl1(wl1[i].x); u1[i].y = dpp_shl1(wl1[i].y);
          u2[i].x = dpp_shl1(wl2[i].x); u2[i].y = dpp_shl1(wl2[i].y);
        }
        float nU1 = dpp_shl1(nL1), nU2 = dpp_shl1(nL2);
        v2f da1 = (v2f)(0.f), da2 = (v2f)(0.f);
        #pragma unroll
        for (int i = 0; i < 11; ++i) { da1 += wr1[i]*u1[i]; da2 += wr2[i]*u2[i]; }
        float d1 = da1.x + da1.y, d2v = da2.x + da2.y;
        d1 = act ? d1 : 0.f;  d2v = act ? d2v : 0.f;
        dacc1 += d1*d1; dacc2 += d2v*d2v;
        float c1, s1, c21, ss1, cs21; rot_cs(nR1, nU1, d1,  c1, s1, c21, ss1, cs21);
        float c2_, s2_, c22, ss2, cs22; rot_cs(nR2, nU2, d2v, c2_, s2_, c22, ss2, cs22);
        v2f cv1 = (v2f)(c1), sv1 = (v2f)(s1);
        v2f cv2 = (v2f)(c2_), sv2 = (v2f)(s2_);
        #pragma unroll
        for (int i = 0; i < 11; ++i) {
          v2f rl1 = cv1*wr1[i] - sv1*u1[i];
          v2f rr1 = sv1*wr1[i] + cv1*u1[i];
          wr1[i].x = act ? rr1.x : wr1[i].x;
          wr1[i].y = act ? rr1.y : wr1[i].y;
          wl1[i].x = upd_shr1(wl1[i].x, rl1.x);
          wl1[i].y = upd_shr1(wl1[i].y, rl1.y);
          v2f rl2 = cv2*wr2[i] - sv2*u2[i];
          v2f rr2 = sv2*wr2[i] + cv2*u2[i];
          wr2[i].x = act ? rr2.x : wr2[i].x;
          wr2[i].y = act ? rr2.y : wr2[i].y;
          wl2[i].x = upd_shr1(wl2[i].x, rl2.x);
          wl2[i].y = upd_shr1(wl2[i].y, rl2.y);
        }
        float nRn1 = ss1*nR1 + cs21*d1 + c21*nU1;
        float nLg1 = c21*nR1 - cs21*d1 + ss1*nU1;
        nR1 = act ? nRn1 : nR1;
        nL1 = upd_shr1(nL1, nLg1);
        float nRn2 = ss2*nR2 + cs22*d2v + c22*nU2;
        float nLg2 = c22*nR2 - cs22*d2v + ss2*nU2;
        nR2 = act ? nRn2 : nR2;
        nL2 = upd_shr1(nL2, nLg2);
      }
    }
    float ds1 = inert ? 0.f : dacc1;
    float ds2 = inert ? 0.f : dacc2;
    ds1 += __shfl_xor(ds1, 1, 16);  ds2 += __shfl_xor(ds2, 1, 16);
    ds1 += __shfl_xor(ds1, 2, 16);  ds2 += __shfl_xor(ds2, 2, 16);
    ds1 += __shfl_xor(ds1, 4, 16);  ds2 += __shfl_xor(ds2, 4, 16);
    ds1 += __shfl_xor(ds1, 8, 16);  ds2 += __shfl_xor(ds2, 8, 16);
    okprev = (ds1 <= eps2*q1) && (ds2 <= eps2*q2);
  }
}

// ---------------- prep: NS(bn,rm) -> S -> per-h Vt, V, D, G ----------------
// Coupled Newton-Schulz (all 256 threads, LDS matmuls):
//   A' = A/||A||_F ; Y0=A', Z0=I
//   T = 3I - Z@Y ; Y <- 0.5*Y@T ; Z <- 0.5*T@Z     (K=11 iterations)
// S = rm^{-1/2} @ bn^{1/2} = sqrt(c_bn/c_rm) * Z_rm @ Y_bn.
__global__ void prep_kernel(const float* __restrict__ rm, const float* __restrict__ bn,
                            const float* __restrict__ W1, const float* __restrict__ W2,
                            const float* __restrict__ conv_w, const float* __restrict__ fc_w,
                            const float* __restrict__ conv_b, const float* __restrict__ fc_b,
                            float* __restrict__ ws, float* __restrict__ out) {
  __shared__ float sW1[1024] __attribute__((aligned(16)));
  __shared__ float sW2[704]  __attribute__((aligned(16)));
  __shared__ float sY[2][2][484] __attribute__((aligned(16)));  // [mat][buf][..]
  __shared__ float sZ[2][2][484] __attribute__((aligned(16)));
  __shared__ float sT[2][484]    __attribute__((aligned(16)));
  __shared__ float sS[484]  __attribute__((aligned(16)));
  __shared__ float sU[704]  __attribute__((aligned(16)));
  __shared__ float sE[220]  __attribute__((aligned(16)));
  __shared__ float sG[1936] __attribute__((aligned(16)));
  __shared__ float sC[2];
  const int tid = threadIdx.x, h = blockIdx.x;

  if (h == 0)  // zero the atomic-add target (replaces memset dispatch)
    for (int idx = tid; idx < 2048; idx += 256) out[idx] = 0.f;

  // phase A: waves 0/1 compute Frobenius norms of bn/rm; waves 2/3 stage W1,W2
  const int wv = tid >> 6, ln = tid & 63;
  if (wv < 2) {
    const float* src = wv ? rm : bn;
    float s = 0.f;
    for (int i = ln; i < 484; i += 64) { float v = src[i]; s += v*v; }
    s += __shfl_xor(s, 1);  s += __shfl_xor(s, 2);  s += __shfl_xor(s, 4);
    s += __shfl_xor(s, 8);  s += __shfl_xor(s, 16); s += __shfl_xor(s, 32);
    if (ln == 0) sC[wv] = sqrtf(s);
  } else {
    const int t = tid - 128;
    for (int i = t; i < 1024; i += 128) sW1[i] = W1[h*1024 + i];
    for (int i = t; i < 704;  i += 128) sW2[i] = W2[h*704 + i];
  }
  __syncthreads();

  // phase B: init Y = A/c, Z = I for both matrices
  {
    const float ic0 = 1.0f/sC[0], ic1 = 1.0f/sC[1];
    for (int idx = tid; idx < 484; idx += 256) {
      const int i = idx/22, j = idx - 22*i;
      const float e = (i == j) ? 1.f : 0.f;
      sY[0][0][idx] = bn[idx]*ic0;  sZ[0][0][idx] = e;
      sY[1][0][idx] = rm[idx]*ic1;  sZ[1][0][idx] = e;
    }
  }
  __syncthreads();

  // phase C: K=11 coupled NS iterations (v2f column pairs: 22 rows x 11 pairs)
  int cur = 0;
  #pragma unroll 1
  for (int it = 0; it < 11; ++it) {
    // T = 3I - Z@Y (both matrices: 484 v2f elements)
    for (int idx = tid; idx < 484; idx += 256) {
      const int mt = (idx >= 242), r = idx - mt*242, i = r/11, jp = r - 11*i;
      const float* Zc = sZ[mt][cur];
      const float* Yc = sY[mt][cur];
      v2f acc = (v2f)(0.f);
      #pragma unroll
      for (int k = 0; k < 22; ++k)
        acc += *(const v2f*)(Yc + k*22 + 2*jp) * Zc[i*22 + k];
      v2f tv;
      tv.x = ((2*jp     == i) ? 3.f : 0.f) - acc.x;
      tv.y = ((2*jp + 1 == i) ? 3.f : 0.f) - acc.y;
      *(v2f*)(sT[mt] + i*22 + 2*jp) = tv;
    }
    __syncthreads();
    // Ynew = 0.5*Y@T ; Znew = 0.5*T@Z  (968 v2f elements)
    for (int idx = tid; idx < 968; idx += 256) {
      const int sel = idx/242, r = idx - 242*sel, i = r/11, jp = r - 11*i;
      const int mt = sel >> 1; const bool isZ = sel & 1;
      const float* A = isZ ? sT[mt] : sY[mt][cur];
      const float* B = isZ ? sZ[mt][cur] : sT[mt];
      v2f acc = (v2f)(0.f);
      #pragma unroll
      for (int k = 0; k < 22; ++k)
        acc += *(const v2f*)(B + k*22 + 2*jp) * A[i*22 + k];
      *(v2f*)((isZ ? sZ[mt][cur^1] : sY[mt][cur^1]) + i*22 + 2*jp) = 0.5f*acc;
    }
    __syncthreads();
    cur ^= 1;   // data now lives in buffer 'cur'
  }

  // phase D: S = sqrt(c_bn/c_rm)*Z_rm@Y_bn ; U = W1@W2 ; raw G (coalesced)
  {
    const float scale = sqrtf(sC[0]/sC[1]);
    const float* Zrm = sZ[1][cur];
    const float* Ybn = sY[0][cur];
    for (int idx = tid; idx < 484; idx += 256) {
      const int i = idx/22, j = idx - 22*i;
      float s = 0.f;
      for (int k = 0; k < 22; ++k) s += Zrm[i*22+k]*Ybn[k*22+j];
      sS[idx] = scale*s;
    }
  }
  for (int idx = tid; idx < 704; idx += 256) {
    const int n = idx/22, j = idx - 22*n;
    float s = 0.f;
    for (int k = 0; k < 32; ++k) s += sW1[n*32+k]*sW2[k*22+j];
    sU[idx] = s;
  }
  // raw G, coalesced: thread t owns v2f element r = 2t,2t+1 of all 4 outputs.
  if (tid < 242) {
    const int wi = h/9, bi = h - 9*wi;
    const float* base = conv_w + wi*4356 + bi*484 + 2*tid;
    v2f a0 = (v2f)(0.f), a1 = (v2f)(0.f), a2 = (v2f)(0.f), a3 = (v2f)(0.f);
    #pragma unroll
    for (int c = 0; c < 48; ++c) {
      const v2f wv2 = *(const v2f*)(base + c*13068);
      a0 += wv2*fc_w[c];
      a1 += wv2*fc_w[48+c];
      a2 += wv2*fc_w[96+c];
      a3 += wv2*fc_w[144+c];
    }
    *(v2f*)(sG +        2*tid) = a0;
    *(v2f*)(sG +  484 + 2*tid) = a1;
    *(v2f*)(sG +  968 + 2*tid) = a2;
    *(v2f*)(sG + 1452 + 2*tid) = a3;
  }
  __syncthreads();

  // V = U_top @ S: write transposed (Vt, packed) and row-major (stride 24)
  for (int idx = tid; idx < 484; idx += 256) {
    const int k = idx/22, j = idx - 22*k;
    float s = 0.f;
    for (int l = 0; l < 22; ++l) s += sU[k*22+l]*sS[l*22+j];
    ws[WS_VT + h*484 + j*22 + k] = s;
    ws[WS_V  + h*V_STRIDE + k*24 + j] = s;
  }
  // E = U_bot @ S (10x22)
  for (int idx = tid; idx < 220; idx += 256) {
    const int e = idx/22, j = idx - 22*e;
    float s = 0.f;
    for (int l = 0; l < 22; ++l) s += sU[(22+e)*22+l]*sS[l*22+j];
    sE[idx] = s;
  }
  __syncthreads();
  // D = E^T E (22x22, symmetric)
  for (int idx = tid; idx < 484; idx += 256) {
    const int i = idx/22, j = idx - 22*i;
    float s = 0.f;
    for (int e = 0; e < 10; ++e) s += sE[e*22+i]*sE[e*22+j];
    ws[WS_D + h*484 + idx] = s;
  }
  // G symmetrized + HALF-SCALED into padded layout:
  //   Gs[i][j] = 2*Gsym_ij (j<i), Gsym_ii (j==i), 0 (j>i)
  for (int idx = tid; idx < 1936; idx += 256) {
    const int o = idx/484, r = idx - 484*o, i = r/22, j = r - 22*i;
    const float v = 0.5f*(sG[o*484 + i*22 + j] + sG[o*484 + j*22 + i]);
    const float gs = (j < i) ? 2.0f*v : ((j == i) ? v : 0.0f);
    ws[WS_G + (o*27+h)*G_STRIDE + i*24 + j] = gs;
  }
  if (h == 0 && tid < 4) {
    float s = 0.f;
    for (int c = 0; c < 48; ++c) s += fc_w[tid*48+c]*conv_b[c];
    ws[WS_CONST + tid] = s + fc_b[tid];
  }
}

// ---------------- main: P4 build + dual Jacobi + projection ----------------
// h wave-uniform -> V/D/G loads scalar AND shared across the two matrices.
// Grid 1728 = 27*64; each 16-lane group owns matrices b1=bb+g, b2=bb+4+g.
__global__ void __launch_bounds__(64, 2) main_kernel(const float* __restrict__ x,
                                                     const float* __restrict__ ws,
                                                     float* __restrict__ out) {
  const int lane = threadIdx.x;
  const int g = lane >> 4, m = lane & 15;
  const int mm = (m < 10) ? m : 10;          // lanes 11..15 mirror pair 10 (inert)
  const int h  = blockIdx.x % 27;            // wave-uniform
  const int bb = (blockIdx.x/27)*8;
  const int b1 = bb + g, b2 = bb + 4 + g;
  const size_t id1 = (size_t)(b1*27 + h), id2 = (size_t)(b2*27 + h);

  // init w = D rows 2mm,2mm+1 (shared: same h for both matrices)
  v2f wl1[11], wr1[11], wl2[11], wr2[11];
  {
    const v2f* d2 = (const v2f*)(ws + WS_D + h*484 + mm*44);
    #pragma unroll
    for (int j = 0; j < 11; ++j) {
      v2f a = d2[j], bvv = d2[11+j];
      wl1[j] = a; wl2[j] = a;
      wr1[j] = bvv; wr2[j] = bvv;
    }
  }
  // streamed build, both matrices sharing vl/vrr and V rows
  {
    v2f vl[11], vrr[11];
    const v2f* vb = (const v2f*)(ws + WS_VT + h*484 + mm*44);
    #pragma unroll
    for (int j = 0; j < 11; ++j) { vl[j] = vb[j]; vrr[j] = vb[11+j]; }
    const v2f* Xa = (const v2f*)(x + id1 * 484);
    const v2f* Xb = (const v2f*)(x + id2 * 484);
    const float* Vrow = ws + WS_V + h*V_STRIDE;
    #pragma unroll 2
    for (int k = 0; k < 22; ++k) {
      v2f aL1 = (v2f)(0.f), aR1 = (v2f)(0.f), aL2 = (v2f)(0.f), aR2 = (v2f)(0.f);
      #pragma unroll
      for (int c = 0; c < 11; ++c) {
        v2f xv1 = Xa[11*k + c], xv2 = Xb[11*k + c];
        aL1 += xv1*vl[c];  aR1 += xv1*vrr[c];
        aL2 += xv2*vl[c];  aR2 += xv2*vrr[c];
      }
      float tL1 = aL1.x + aL1.y, tR1 = aR1.x + aR1.y;
      float tL2 = aL2.x + aL2.y, tR2 = aR2.x + aR2.y;
      const v2f* vk = (const v2f*)(Vrow + k*24);
      #pragma unroll
      for (int j = 0; j < 11; ++j) {
        v2f q = vk[j];
        wl1[j] += q*tL1;  wr1[j] += q*tR1;
        wl2[j] += q*tL2;  wr2[j] += q*tR2;
      }
    }
  }

  jacobi_sweeps2(wl1, wr1, wl2, wr2, (m < 10), (m > 10), 2, 1e-4f);

  // log-eig coefficients for both matrices
  float nL1, nR1, nL2, nR2;
  {
    v2f a1 = (v2f)(0.f), bq1 = (v2f)(0.f), a2 = (v2f)(0.f), bq2 = (v2f)(0.f);
    #pragma unroll
    for (int i = 0; i < 11; ++i) {
      a1 += wl1[i]*wl1[i]; bq1 += wr1[i]*wr1[i];
      a2 += wl2[i]*wl2[i]; bq2 += wr2[i]*wr2[i];
    }
    nL1 = a1.x + a1.y; nR1 = bq1.x + bq1.y;
    nL2 = a2.x + a2.y; nR2 = bq2.x + bq2.y;
  }
  const float HALF_LN2 = 0.34657359f;        // 0.5*ln(2)
  float coefL1 = HALF_LN2*log2f(fmaxf(nL1, 1e-8f))*__builtin_amdgcn_rcpf(nL1);
  float coefR1 = HALF_LN2*log2f(fmaxf(nR1, 1e-8f))*__builtin_amdgcn_rcpf(nR1);
  float coefL2 = HALF_LN2*log2f(fmaxf(nL2, 1e-8f))*__builtin_amdgcn_rcpf(nL2);
  float coefR2 = HALF_LN2*log2f(fmaxf(nR2, 1e-8f))*__builtin_amdgcn_rcpf(nR2);

  // triangle projection, G loads shared across both matrices
  #pragma unroll 1
  for (int o = 0; o < 4; ++o) {
    const float* Gptr = ws + WS_G + (o*27+h)*G_STRIDE;
    float qL1 = 0.f, qR1 = 0.f, qL2 = 0.f, qR2 = 0.f;
    #pragma unroll
    for (int k = 0; k < 22; ++k) {
      const v2f* g2 = (const v2f*)(Gptr + k*24);
      v2f sa1 = (v2f)(0.f), ra1 = (v2f)(0.f), sa2 = (v2f)(0.f), ra2 = (v2f)(0.f);
      #pragma unroll
      for (int j = 0; j <= (k>>1); ++j) {     // Gs zero beyond column k
        v2f q = g2[j];
        sa1 += q*wl1[j];  ra1 += q*wr1[j];
        sa2 += q*wl2[j];  ra2 += q*wr2[j];
      }
      float wL1 = wl1[k>>1][k&1], wR1 = wr1[k>>1][k&1];
      float wL2 = wl2[k>>1][k&1], wR2 = wr2[k>>1][k&1];
      qL1 += wL1*(sa1.x + sa1.y);  qR1 += wR1*(ra1.x + ra1.y);
      qL2 += wL2*(sa2.x + sa2.y);  qR2 += wR2*(ra2.x + ra2.y);
    }
    float v1 = (m <= 10) ? (coefL1*qL1 + coefR1*qR1) : 0.0f;
    float v2 = (m <= 10) ? (coefL2*qL2 + coefR2*qR2) : 0.0f;
    v1 += __shfl_down(v1, 8, 16);  v2 += __shfl_down(v2, 8, 16);
    v1 += __shfl_down(v1, 4, 16);  v2 += __shfl_down(v2, 4, 16);
    v1 += __shfl_down(v1, 2, 16);  v2 += __shfl_down(v2, 2, 16);
    v1 += __shfl_down(v1, 1, 16);  v2 += __shfl_down(v2, 1, 16);
    if (m == 0) {
      if (h == 0) { v1 += ws[WS_CONST + o]; v2 += ws[WS_CONST + o]; }
      atomicAdd(out + b1*4 + o, v1);
      atomicAdd(out + b2*4 + o, v2);
    }
  }
}

extern "C" void kernel_launch(void* const* d_in, const int* in_sizes, int n_in,
                              void* d_out, int out_size, void* d_ws, size_t ws_size,
                              hipStream_t stream) {
  const float* x   = (const float*)d_in[0];
  const float* W1  = (const float*)d_in[1];
  const float* W2  = (const float*)d_in[2];
  const float* rm  = (const float*)d_in[3];
  const float* bn  = (const float*)d_in[4];
  const float* cw  = (const float*)d_in[5];
  const float* cb  = (const float*)d_in[6];
  const float* fw  = (const float*)d_in[7];
  const float* fb  = (const float*)d_in[8];
  float* out = (float*)d_out;
  float* ws  = (float*)d_ws;

  prep_kernel<<<27, 256, 0, stream>>>(rm, bn, W1, W2, cw, fw, cb, fb, ws, out);
  main_kernel<<<1728, 64, 0, stream>>>(x, ws, out);
}

// Round 12
// 257.314 us; speedup vs baseline: 1.0784x; 1.0113x over previous
//
#include <hip/hip_runtime.h>

// ---------------------------------------------------------------------------
// Tensor_CSPNet forward, restructured:
//   out[b,o] = sum_h <G[o,h], log(V_h^T X[b,h] V_h + D_h)> + const[o]
// ReEig stages are provably no-ops (all eigenvalues >= 0.5 >> 1e-4).
// R16: prep Jacobi(bn,rm) -> block-parallel coupled Newton-Schulz (-13us).
// R17: prep G-pass coalesced (-9us).
// R18: FAILED. launch_bounds(256,8) -> 32-VGPR squeeze -> scratch spill.
// R19: FAILED. 4-wave blocks: occupancy is GRID/equilibrium-limited.
// R20: WIN (-40us main). Odd-even transposition (Brent-Luk) ordering.
// R21: WIN (-11us main). Direct c,s rotation + update_dpp boundary merge.
// R22/R23: FAILED. v_pk_fma_f32: scalar v_fma IS the gfx950 fp32 peak.
// R24: FAILED accuracy: eps2 3e-3 too loose. eps2=1e-4 is the boundary.
// R25: WIN (-8us main). Triangle projection (exact) at eps2=1e-4.
// R26: NEUTRAL. Dual-matrix ILP: main 170->168, VALUBusy unchanged 65%.
//   TLP/ILP/packing all falsified -> main ~168us is the structural floor
//   at this instruction count. Kept (marginally ahead).
// R27: prep polish targeting the stable 88-92us bench-main gap:
//   (a) NS K 11->8: lambda'min(bn)~0.1 -> (1-l')^{2^8} ~ 1e-9, fp32-exact;
//       -27% of the NS critical path.
//   (b) G-pass (48 cold strided conv_w loads) interleaved 6-per-NS-iter
//       so HBM latency hides under NS compute instead of an exposed
//       phase-D block.
//   Decision rule: bench ~258-262 after this => residual gap is
//   harness-fixed (reset memsets/launch) => declare roofline.
// ---------------------------------------------------------------------------

#define WS_CONST 484                     // 4     : fc_w@conv_b + fc_b
#define WS_VT    512                     // 27*484: Vt[h][j][k] = V_h[k][j]
#define WS_V     (512 + 13068)           // 27*528: V[h][k][j], rows padded to 24
#define WS_D     (13580 + 14256)         // 27*484: D_h row-major (sym)
#define WS_G     (27836 + 13068)         // 4*27*528: Gs[o][h] half-scaled, rows padded to 24
#define G_STRIDE 528
#define V_STRIDE 528

typedef float v2f __attribute__((ext_vector_type(2)));

static __device__ __forceinline__ float dpp_shl1(float x) { // lane m <- lane m+1 (within 16-row)
  return __int_as_float(__builtin_amdgcn_mov_dpp(__float_as_int(x), 0x101, 0xf, 0xf, true));
}
// lane m <- lane m-1 within 16-row; lane 0 of each row KEEPS old (bound_ctrl=false)
static __device__ __forceinline__ float upd_shr1(float old, float x) {
  return __int_as_float(__builtin_amdgcn_update_dpp(
      __float_as_int(old), __float_as_int(x), 0x111, 0xf, 0xf, false));
}

// Direct Jacobi rotation from Gram entries (nL, d, nR):
//   mu = (nR-nL)/2; r = sqrt(mu^2+d^2); cos2t = |mu|/r (inner rotation)
//   c = sqrt((1+cos2t)/2); cs2 = 2cs = sign(mu)*d/r; s = cs2/(2c)
static __device__ __forceinline__ void rot_cs(float nL, float nR, float d,
                                              float& c, float& s,
                                              float& c2, float& ss, float& cs2) {
  float mu   = 0.5f*(nR - nL);
  float r2   = __builtin_fmaf(mu, mu, d*d);
  float invr = __builtin_amdgcn_rsqf(r2);
  bool  degen = (r2 < 1e-40f);
  float co = fminf(fabsf(mu)*invr, 1.0f);
  co = degen ? 1.0f : co;
  c2 = __builtin_fmaf(0.5f, co, 0.5f);
  c  = sqrtf(c2);
  float cinv = __builtin_amdgcn_rcpf(c);
  float t2 = d*invr;
  t2 = (mu < 0.0f) ? -t2 : t2;
  cs2 = degen ? 0.0f : t2;
  s  = 0.5f*cs2*cinv;
  ss = 1.0f - c2;
}

// One-sided Jacobi, odd-even transposition (Brent-Luk), TWO matrices per
// thread interleaved so their serial rotation chains cover each other's
// latency. Lane m holds cols (2m,2m+1) of both; lanes 11..15 inert.
static __device__ __forceinline__ void jacobi_sweeps2(v2f wl1[11], v2f wr1[11],
                                                      v2f wl2[11], v2f wr2[11],
                                                      bool act, bool inert,
                                                      int minsweep, float eps2) {
  int okprev = 0;
  #pragma unroll 1
  for (int sweep = 0; sweep < 5; ++sweep) {
    if (sweep >= minsweep && __all(okprev)) break;
    // fresh norms each sweep
    v2f na1 = (v2f)(0.f), nb1 = (v2f)(0.f), na2 = (v2f)(0.f), nb2 = (v2f)(0.f);
    #pragma unroll
    for (int i = 0; i < 11; ++i) {
      na1 += wl1[i]*wl1[i]; nb1 += wr1[i]*wr1[i];
      na2 += wl2[i]*wl2[i]; nb2 += wr2[i]*wr2[i];
    }
    float nL1 = na1.x + na1.y, nR1 = nb1.x + nb1.y;
    float nL2 = na2.x + na2.y, nR2 = nb2.x + nb2.y;
    float q1 = inert ? 0.f : (nL1*nL1 + nR1*nR1);
    float q2 = inert ? 0.f : (nL2*nL2 + nR2*nR2);
    q1 += __shfl_xor(q1, 1, 16);  q2 += __shfl_xor(q2, 1, 16);
    q1 += __shfl_xor(q1, 2, 16);  q2 += __shfl_xor(q2, 2, 16);
    q1 += __shfl_xor(q1, 4, 16);  q2 += __shfl_xor(q2, 4, 16);
    q1 += __shfl_xor(q1, 8, 16);  q2 += __shfl_xor(q2, 8, 16);
    float dacc1 = 0.f, dacc2 = 0.f;
    #pragma unroll 1
    for (int r = 0; r < 11; ++r) {
      // ---------- step A: rotate intra-lane pairs; swap by rename ----------
      {
        v2f da1 = (v2f)(0.f), da2 = (v2f)(0.f);
        #pragma unroll
        for (int i = 0; i < 11; ++i) { da1 += wl1[i]*wr1[i]; da2 += wl2[i]*wr2[i]; }
        float d1 = da1.x + da1.y, d2v = da2.x + da2.y;
        dacc1 += d1*d1; dacc2 += d2v*d2v;
        float c1, s1, c21, ss1, cs21; rot_cs(nL1, nR1, d1,  c1, s1, c21, ss1, cs21);
        float c2_, s2_, c22, ss2, cs22; rot_cs(nL2, nR2, d2v, c2_, s2_, c22, ss2, cs22);
        float nLn1 = c21*nL1 - cs21*d1 + ss1*nR1;
        float nRn1 = ss1*nL1 + cs21*d1 + c21*nR1;
        float nLn2 = c22*nL2 - cs22*d2v + ss2*nR2;
        float nRn2 = ss2*nL2 + cs22*d2v + c22*nR2;
        v2f cv1 = (v2f)(c1), sv1 = (v2f)(s1);
        v2f cv2 = (v2f)(c2_), sv2 = (v2f)(s2_);
        #pragma unroll
        for (int i = 0; i < 11; ++i) {
          v2f nl1 = cv1*wl1[i] - sv1*wr1[i];
          v2f nr1 = sv1*wl1[i] + cv1*wr1[i];
          wl1[i] = nr1; wr1[i] = nl1;
          v2f nl2 = cv2*wl2[i] - sv2*wr2[i];
          v2f nr2 = sv2*wl2[i] + cv2*wr2[i];
          wl2[i] = nr2; wr2[i] = nl2;
        }
        nL1 = nRn1; nR1 = nLn1;
        nL2 = nRn2; nR2 = nLn2;
      }
      // ---------- step B: u = shl(wl); rotate (wr, u), lanes m<10 ----------
      {
        v2f u1[11], u2[11];
        #pragma unroll
        for (int i = 0; i < 11; ++i) {
          u1[i].x = dpp_shl1(wl1[i].x); u1[i].y = dpp_shl1(wl1[i].y);
          u2[i].x = dpp_shl1(wl2[i].x); u2[i].y = dpp_shl1(wl2[i].y);
        }
        float nU1 = dpp_shl1(nL1), nU2 = dpp_shl1(nL2);
        v2f da1 = (v2f)(0.f), da2 = (v2f)(0.f);
        #pragma unroll
        for (int i = 0; i < 11; ++i) { da1 += wr1[i]*u1[i]; da2 += wr2[i]*u2[i]; }
        float d1 = da1.x + da1.y, d2v = da2.x + da2.y;
        d1 = act ? d1 : 0.f;  d2v = act ? d2v : 0.f;
        dacc1 += d1*d1; dacc2 += d2v*d2v;
        float c1, s1, c21, ss1, cs21; rot_cs(nR1, nU1, d1,  c1, s1, c21, ss1, cs21);
        float c2_, s2_, c22, ss2, cs22; rot_cs(nR2, nU2, d2v, c2_, s2_, c22, ss2, cs22);
        v2f cv1 = (v2f)(c1), sv1 = (v2f)(s1);
        v2f cv2 = (v2f)(c2_), sv2 = (v2f)(s2_);
        #pragma unroll
        for (int i = 0; i < 11; ++i) {
          v2f rl1 = cv1*wr1[i] - sv1*u1[i];
          v2f rr1 = sv1*wr1[i] + cv1*u1[i];
          wr1[i].x = act ? rr1.x : wr1[i].x;
          wr1[i].y = act ? rr1.y : wr1[i].y;
          wl1[i].x = upd_shr1(wl1[i].x, rl1.x);
          wl1[i].y = upd_shr1(wl1[i].y, rl1.y);
          v2f rl2 = cv2*wr2[i] - sv2*u2[i];
          v2f rr2 = sv2*wr2[i] + cv2*u2[i];
          wr2[i].x = act ? rr2.x : wr2[i].x;
          wr2[i].y = act ? rr2.y : wr2[i].y;
          wl2[i].x = upd_shr1(wl2[i].x, rl2.x);
          wl2[i].y = upd_shr1(wl2[i].y, rl2.y);
        }
        float nRn1 = ss1*nR1 + cs21*d1 + c21*nU1;
        float nLg1 = c21*nR1 - cs21*d1 + ss1*nU1;
        nR1 = act ? nRn1 : nR1;
        nL1 = upd_shr1(nL1, nLg1);
        float nRn2 = ss2*nR2 + cs22*d2v + c22*nU2;
        float nLg2 = c22*nR2 - cs22*d2v + ss2*nU2;
        nR2 = act ? nRn2 : nR2;
        nL2 = upd_shr1(nL2, nLg2);
      }
    }
    float ds1 = inert ? 0.f : dacc1;
    float ds2 = inert ? 0.f : dacc2;
    ds1 += __shfl_xor(ds1, 1, 16);  ds2 += __shfl_xor(ds2, 1, 16);
    ds1 += __shfl_xor(ds1, 2, 16);  ds2 += __shfl_xor(ds2, 2, 16);
    ds1 += __shfl_xor(ds1, 4, 16);  ds2 += __shfl_xor(ds2, 4, 16);
    ds1 += __shfl_xor(ds1, 8, 16);  ds2 += __shfl_xor(ds2, 8, 16);
    okprev = (ds1 <= eps2*q1) && (ds2 <= eps2*q2);
  }
}

// ---------------- prep: NS(bn,rm) -> S -> per-h Vt, V, D, G ----------------
// Coupled Newton-Schulz (all 256 threads, LDS matmuls), K=8 iterations:
//   A' = A/||A||_F ; Y0=A', Z0=I
//   T = 3I - Z@Y ; Y <- 0.5*Y@T ; Z <- 0.5*T@Z
//   lambda'min ~ 0.1 -> (1-l')^{2^8} ~ 1e-9: fp32-exact at K=8.
// G-pass (48 strided conv_w loads) interleaved 6-per-NS-iteration so the
// cold HBM latency hides under NS compute.
// S = rm^{-1/2} @ bn^{1/2} = sqrt(c_bn/c_rm) * Z_rm @ Y_bn.
__global__ void prep_kernel(const float* __restrict__ rm, const float* __restrict__ bn,
                            const float* __restrict__ W1, const float* __restrict__ W2,
                            const float* __restrict__ conv_w, const float* __restrict__ fc_w,
                            const float* __restrict__ conv_b, const float* __restrict__ fc_b,
                            float* __restrict__ ws, float* __restrict__ out) {
  __shared__ float sW1[1024] __attribute__((aligned(16)));
  __shared__ float sW2[704]  __attribute__((aligned(16)));
  __shared__ float sY[2][2][484] __attribute__((aligned(16)));  // [mat][buf][..]
  __shared__ float sZ[2][2][484] __attribute__((aligned(16)));
  __shared__ float sT[2][484]    __attribute__((aligned(16)));
  __shared__ float sS[484]  __attribute__((aligned(16)));
  __shared__ float sU[704]  __attribute__((aligned(16)));
  __shared__ float sE[220]  __attribute__((aligned(16)));
  __shared__ float sG[1936] __attribute__((aligned(16)));
  __shared__ float sC[2];
  const int tid = threadIdx.x, h = blockIdx.x;

  if (h == 0)  // zero the atomic-add target (replaces memset dispatch)
    for (int idx = tid; idx < 2048; idx += 256) out[idx] = 0.f;

  // G-pass accumulators (filled inside the NS loop, 6 c-steps/iter)
  const int wi = h/9, bi = h - 9*wi;
  const float* gbase = conv_w + wi*4356 + bi*484 + 2*tid;
  v2f ga0 = (v2f)(0.f), ga1 = (v2f)(0.f), ga2 = (v2f)(0.f), ga3 = (v2f)(0.f);

  // phase A: waves 0/1 compute Frobenius norms of bn/rm; waves 2/3 stage W1,W2
  const int wv = tid >> 6, ln = tid & 63;
  if (wv < 2) {
    const float* src = wv ? rm : bn;
    float s = 0.f;
    for (int i = ln; i < 484; i += 64) { float v = src[i]; s += v*v; }
    s += __shfl_xor(s, 1);  s += __shfl_xor(s, 2);  s += __shfl_xor(s, 4);
    s += __shfl_xor(s, 8);  s += __shfl_xor(s, 16); s += __shfl_xor(s, 32);
    if (ln == 0) sC[wv] = sqrtf(s);
  } else {
    const int t = tid - 128;
    for (int i = t; i < 1024; i += 128) sW1[i] = W1[h*1024 + i];
    for (int i = t; i < 704;  i += 128) sW2[i] = W2[h*704 + i];
  }
  __syncthreads();

  // phase B: init Y = A/c, Z = I for both matrices
  {
    const float ic0 = 1.0f/sC[0], ic1 = 1.0f/sC[1];
    for (int idx = tid; idx < 484; idx += 256) {
      const int i = idx/22, j = idx - 22*i;
      const float e = (i == j) ? 1.f : 0.f;
      sY[0][0][idx] = bn[idx]*ic0;  sZ[0][0][idx] = e;
      sY[1][0][idx] = rm[idx]*ic1;  sZ[1][0][idx] = e;
    }
  }
  __syncthreads();

  // phase C: K=8 coupled NS iterations (v2f column pairs: 22 rows x 11 pairs)
  // + 6 G-pass c-steps per iteration (48 total)
  int cur = 0;
  #pragma unroll 1
  for (int it = 0; it < 8; ++it) {
    // T = 3I - Z@Y (both matrices: 484 v2f elements)
    for (int idx = tid; idx < 484; idx += 256) {
      const int mt = (idx >= 242), r = idx - mt*242, i = r/11, jp = r - 11*i;
      const float* Zc = sZ[mt][cur];
      const float* Yc = sY[mt][cur];
      v2f acc = (v2f)(0.f);
      #pragma unroll
      for (int k = 0; k < 22; ++k)
        acc += *(const v2f*)(Yc + k*22 + 2*jp) * Zc[i*22 + k];
      v2f tv;
      tv.x = ((2*jp     == i) ? 3.f : 0.f) - acc.x;
      tv.y = ((2*jp + 1 == i) ? 3.f : 0.f) - acc.y;
      *(v2f*)(sT[mt] + i*22 + 2*jp) = tv;
    }
    __syncthreads();
    // Ynew = 0.5*Y@T ; Znew = 0.5*T@Z  (968 v2f elements)
    for (int idx = tid; idx < 968; idx += 256) {
      const int sel = idx/242, r = idx - 242*sel, i = r/11, jp = r - 11*i;
      const int mt = sel >> 1; const bool isZ = sel & 1;
      const float* A = isZ ? sT[mt] : sY[mt][cur];
      const float* B = isZ ? sZ[mt][cur] : sT[mt];
      v2f acc = (v2f)(0.f);
      #pragma unroll
      for (int k = 0; k < 22; ++k)
        acc += *(const v2f*)(B + k*22 + 2*jp) * A[i*22 + k];
      *(v2f*)((isZ ? sZ[mt][cur^1] : sY[mt][cur^1]) + i*22 + 2*jp) = 0.5f*acc;
    }
    __syncthreads();
    cur ^= 1;   // data now lives in buffer 'cur'
    // interleaved G-pass: 6 strided conv_w loads + FMAs (no barriers;
    // uniformly reachable -> barrier-safe). Latency hides under next phase.
    if (tid < 242) {
      #pragma unroll
      for (int cc = 0; cc < 6; ++cc) {
        const int c = it*6 + cc;
        const v2f wv2 = *(const v2f*)(gbase + c*13068);
        ga0 += wv2*fc_w[c];
        ga1 += wv2*fc_w[48+c];
        ga2 += wv2*fc_w[96+c];
        ga3 += wv2*fc_w[144+c];
      }
    }
  }

  // commit G-pass accumulators to LDS (read after the next barrier)
  if (tid < 242) {
    *(v2f*)(sG +        2*tid) = ga0;
    *(v2f*)(sG +  484 + 2*tid) = ga1;
    *(v2f*)(sG +  968 + 2*tid) = ga2;
    *(v2f*)(sG + 1452 + 2*tid) = ga3;
  }

  // phase D: S = sqrt(c_bn/c_rm)*Z_rm@Y_bn ; U = W1@W2
  {
    const float scale = sqrtf(sC[0]/sC[1]);
    const float* Zrm = sZ[1][cur];
    const float* Ybn = sY[0][cur];
    for (int idx = tid; idx < 484; idx += 256) {
      const int i = idx/22, j = idx - 22*i;
      float s = 0.f;
      for (int k = 0; k < 22; ++k) s += Zrm[i*22+k]*Ybn[k*22+j];
      sS[idx] = scale*s;
    }
  }
  for (int idx = tid; idx < 704; idx += 256) {
    const int n = idx/22, j = idx - 22*n;
    float s = 0.f;
    for (int k = 0; k < 32; ++k) s += sW1[n*32+k]*sW2[k*22+j];
    sU[idx] = s;
  }
  __syncthreads();

  // V = U_top @ S: write transposed (Vt, packed) and row-major (stride 24)
  for (int idx = tid; idx < 484; idx += 256) {
    const int k = idx/22, j = idx - 22*k;
    float s = 0.f;
    for (int l = 0; l < 22; ++l) s += sU[k*22+l]*sS[l*22+j];
    ws[WS_VT + h*484 + j*22 + k] = s;
    ws[WS_V  + h*V_STRIDE + k*24 + j] = s;
  }
  // E = U_bot @ S (10x22)
  for (int idx = tid; idx < 220; idx += 256) {
    const int e = idx/22, j = idx - 22*e;
    float s = 0.f;
    for (int l = 0; l < 22; ++l) s += sU[(22+e)*22+l]*sS[l*22+j];
    sE[idx] = s;
  }
  __syncthreads();
  // D = E^T E (22x22, symmetric)
  for (int idx = tid; idx < 484; idx += 256) {
    const int i = idx/22, j = idx - 22*i;
    float s = 0.f;
    for (int e = 0; e < 10; ++e) s += sE[e*22+i]*sE[e*22+j];
    ws[WS_D + h*484 + idx] = s;
  }
  // G symmetrized + HALF-SCALED into padded layout:
  //   Gs[i][j] = 2*Gsym_ij (j<i), Gsym_ii (j==i), 0 (j>i)
  for (int idx = tid; idx < 1936; idx += 256) {
    const int o = idx/484, r = idx - 484*o, i = r/22, j = r - 22*i;
    const float v = 0.5f*(sG[o*484 + i*22 + j] + sG[o*484 + j*22 + i]);
    const float gs = (j < i) ? 2.0f*v : ((j == i) ? v : 0.0f);
    ws[WS_G + (o*27+h)*G_STRIDE + i*24 + j] = gs;
  }
  if (h == 0 && tid < 4) {
    float s = 0.f;
    for (int c = 0; c < 48; ++c) s += fc_w[tid*48+c]*conv_b[c];
    ws[WS_CONST + tid] = s + fc_b[tid];
  }
}

// ---------------- main: P4 build + dual Jacobi + projection ----------------
// h wave-uniform -> V/D/G loads scalar AND shared across the two matrices.
// Grid 1728 = 27*64; each 16-lane group owns matrices b1=bb+g, b2=bb+4+g.
__global__ void __launch_bounds__(64, 2) main_kernel(const float* __restrict__ x,
                                                     const float* __restrict__ ws,
                                                     float* __restrict__ out) {
  const int lane = threadIdx.x;
  const int g = lane >> 4, m = lane & 15;
  const int mm = (m < 10) ? m : 10;          // lanes 11..15 mirror pair 10 (inert)
  const int h  = blockIdx.x % 27;            // wave-uniform
  const int bb = (blockIdx.x/27)*8;
  const int b1 = bb + g, b2 = bb + 4 + g;
  const size_t id1 = (size_t)(b1*27 + h), id2 = (size_t)(b2*27 + h);

  // init w = D rows 2mm,2mm+1 (shared: same h for both matrices)
  v2f wl1[11], wr1[11], wl2[11], wr2[11];
  {
    const v2f* d2 = (const v2f*)(ws + WS_D + h*484 + mm*44);
    #pragma unroll
    for (int j = 0; j < 11; ++j) {
      v2f a = d2[j], bvv = d2[11+j];
      wl1[j] = a; wl2[j] = a;
      wr1[j] = bvv; wr2[j] = bvv;
    }
  }
  // streamed build, both matrices sharing vl/vrr and V rows
  {
    v2f vl[11], vrr[11];
    const v2f* vb = (const v2f*)(ws + WS_VT + h*484 + mm*44);
    #pragma unroll
    for (int j = 0; j < 11; ++j) { vl[j] = vb[j]; vrr[j] = vb[11+j]; }
    const v2f* Xa = (const v2f*)(x + id1 * 484);
    const v2f* Xb = (const v2f*)(x + id2 * 484);
    const float* Vrow = ws + WS_V + h*V_STRIDE;
    #pragma unroll 2
    for (int k = 0; k < 22; ++k) {
      v2f aL1 = (v2f)(0.f), aR1 = (v2f)(0.f), aL2 = (v2f)(0.f), aR2 = (v2f)(0.f);
      #pragma unroll
      for (int c = 0; c < 11; ++c) {
        v2f xv1 = Xa[11*k + c], xv2 = Xb[11*k + c];
        aL1 += xv1*vl[c];  aR1 += xv1*vrr[c];
        aL2 += xv2*vl[c];  aR2 += xv2*vrr[c];
      }
      float tL1 = aL1.x + aL1.y, tR1 = aR1.x + aR1.y;
      float tL2 = aL2.x + aL2.y, tR2 = aR2.x + aR2.y;
      const v2f* vk = (const v2f*)(Vrow + k*24);
      #pragma unroll
      for (int j = 0; j < 11; ++j) {
        v2f q = vk[j];
        wl1[j] += q*tL1;  wr1[j] += q*tR1;
        wl2[j] += q*tL2;  wr2[j] += q*tR2;
      }
    }
  }

  jacobi_sweeps2(wl1, wr1, wl2, wr2, (m < 10), (m > 10), 2, 1e-4f);

  // log-eig coefficients for both matrices
  float nL1, nR1, nL2, nR2;
  {
    v2f a1 = (v2f)(0.f), bq1 = (v2f)(0.f), a2 = (v2f)(0.f), bq2 = (v2f)(0.f);
    #pragma unroll
    for (int i = 0; i < 11; ++i) {
      a1 += wl1[i]*wl1[i]; bq1 += wr1[i]*wr1[i];
      a2 += wl2[i]*wl2[i]; bq2 += wr2[i]*wr2[i];
    }
    nL1 = a1.x + a1.y; nR1 = bq1.x + bq1.y;
    nL2 = a2.x + a2.y; nR2 = bq2.x + bq2.y;
  }
  const float HALF_LN2 = 0.34657359f;        // 0.5*ln(2)
  float coefL1 = HALF_LN2*log2f(fmaxf(nL1, 1e-8f))*__builtin_amdgcn_rcpf(nL1);
  float coefR1 = HALF_LN2*log2f(fmaxf(nR1, 1e-8f))*__builtin_amdgcn_rcpf(nR1);
  float coefL2 = HALF_LN2*log2f(fmaxf(nL2, 1e-8f))*__builtin_amdgcn_rcpf(nL2);
  float coefR2 = HALF_LN2*log2f(fmaxf(nR2, 1e-8f))*__builtin_amdgcn_rcpf(nR2);

  // triangle projection, G loads shared across both matrices
  #pragma unroll 1
  for (int o = 0; o < 4; ++o) {
    const float* Gptr = ws + WS_G + (o*27+h)*G_STRIDE;
    float qL1 = 0.f, qR1 = 0.f, qL2 = 0.f, qR2 = 0.f;
    #pragma unroll
    for (int k = 0; k < 22; ++k) {
      const v2f* g2 = (const v2f*)(Gptr + k*24);
      v2f sa1 = (v2f)(0.f), ra1 = (v2f)(0.f), sa2 = (v2f)(0.f), ra2 = (v2f)(0.f);
      #pragma unroll
      for (int j = 0; j <= (k>>1); ++j) {     // Gs zero beyond column k
        v2f q = g2[j];
        sa1 += q*wl1[j];  ra1 += q*wr1[j];
        sa2 += q*wl2[j];  ra2 += q*wr2[j];
      }
      float wL1 = wl1[k>>1][k&1], wR1 = wr1[k>>1][k&1];
      float wL2 = wl2[k>>1][k&1], wR2 = wr2[k>>1][k&1];
      qL1 += wL1*(sa1.x + sa1.y);  qR1 += wR1*(ra1.x + ra1.y);
      qL2 += wL2*(sa2.x + sa2.y);  qR2 += wR2*(ra2.x + ra2.y);
    }
    float v1 = (m <= 10) ? (coefL1*qL1 + coefR1*qR1) : 0.0f;
    float v2 = (m <= 10) ? (coefL2*qL2 + coefR2*qR2) : 0.0f;
    v1 += __shfl_down(v1, 8, 16);  v2 += __shfl_down(v2, 8, 16);
    v1 += __shfl_down(v1, 4, 16);  v2 += __shfl_down(v2, 4, 16);
    v1 += __shfl_down(v1, 2, 16);  v2 += __shfl_down(v2, 2, 16);
    v1 += __shfl_down(v1, 1, 16);  v2 += __shfl_down(v2, 1, 16);
    if (m == 0) {
      if (h == 0) { v1 += ws[WS_CONST + o]; v2 += ws[WS_CONST + o]; }
      atomicAdd(out + b1*4 + o, v1);
      atomicAdd(out + b2*4 + o, v2);
    }
  }
}

extern "C" void kernel_launch(void* const* d_in, const int* in_sizes, int n_in,
                              void* d_out, int out_size, void* d_ws, size_t ws_size,
                              hipStream_t stream) {
  const float* x   = (const float*)d_in[0];
  const float* W1  = (const float*)d_in[1];
  const float* W2  = (const float*)d_in[2];
  const float* rm  = (const float*)d_in[3];
  const float* bn  = (const float*)d_in[4];
  const float* cw  = (const float*)d_in[5];
  const float* cb  = (const float*)d_in[6];
  const float* fw  = (const float*)d_in[7];
  const float* fb  = (const float*)d_in[8];
  float* out = (float*)d_out;
  float* ws  = (float*)d_ws;

  prep_kernel<<<27, 256, 0, stream>>>(rm, bn, W1, W2, cw, fw, cb, fb, ws, out);
  main_kernel<<<1728, 64, 0, stream>>>(x, ws, out);
}